// Round 13
// baseline (1000.474 us; speedup 1.0000x reference)
//
#include <hip/hip_runtime.h>
#include <stdint.h>

// ---------------------------------------------------------------------------
// SeparatedAttention on MI355X (gfx950), fp16 MFMA pipeline (fp32 accum).
// Round 13: GEMM BK 64->32 at constant 8-phase/6-barrier schedule; LDS
// 128KB -> 64KB => 2 blocks/CU (cross-block stall hiding, m114). Swizzle
// sigma_r(c)=c^((r>>1)&3) (2-way free both sides); counted vmcnt(3) ledger
// (1 gload/stage). k_cast+k_tc5 merged into k_prep. Attention frozen (r12).
// ---------------------------------------------------------------------------

typedef __attribute__((ext_vector_type(8))) unsigned short u16x8;
typedef __attribute__((ext_vector_type(8))) _Float16 f16x8;
typedef __attribute__((ext_vector_type(4))) float f32x4;

__device__ __forceinline__ unsigned short f2h(float f) {   // RNE fp32->fp16
  _Float16 h = (_Float16)f;
  return __builtin_bit_cast(unsigned short, h);
}

__device__ __forceinline__ float exp2r(float x) {          // raw v_exp_f32
  return __builtin_amdgcn_exp2f(x);
}

__device__ __forceinline__ void mfma16(f32x4& d, u16x8 a, u16x8 b) {
  d = __builtin_amdgcn_mfma_f32_16x16x32_f16(
      __builtin_bit_cast(f16x8, a), __builtin_bit_cast(f16x8, b), d, 0, 0, 0);
}

// async global->LDS, 16B per lane; dest = wave-uniform base + lane*16
__device__ __forceinline__ void async16(void* lds_p, const void* g) {
  __builtin_amdgcn_global_load_lds(
      (const __attribute__((address_space(1))) unsigned int*)g,
      (__attribute__((address_space(3))) unsigned int*)lds_p, 16, 0, 0);
}

// XOR swizzle for [row][128B] LDS tiles (attention)
__device__ __forceinline__ int swz(int row, int bcol) {
  return (row << 7) + (bcol ^ ((row & 7) << 4));
}

// bijective XCD swizzle (m204)
__device__ __forceinline__ int xcd_swz(int bid, int nwg) {
  int q8 = nwg >> 3, r8 = nwg & 7;
  int xcd = bid & 7, idx = bid >> 3;
  return (xcd < r8 ? xcd * (q8 + 1) : r8 * (q8 + 1) + (xcd - r8) * q8) + idx;
}

// ---------------- workspace layout (bytes) ----------------
static constexpr size_t OFF_XB   = 0;                    // x fp16      108.1MB
static constexpr size_t OFF_QKV  = 108134400;            // qkv fp16    302.0MB
static constexpr size_t OFF_KV   = 410124288;            // kv fp16     201.6MB
static constexpr size_t OFF_QACT = 611713024;            // q_act fp16    7.5MB
static constexpr size_t OFF_ANON = 619184128;            // attn_non    100.7MB
static constexpr size_t OFF_AACT = 719847424;            // attn_act      7.5MB
static constexpr size_t OFF_WQKV = 727318528;            // W^T fp16 ...
static constexpr size_t OFF_WKV  = 733609984;
static constexpr size_t OFF_WQ   = 737804288;
static constexpr size_t OFF_WPN  = 739901440;
static constexpr size_t OFF_WPA  = 741998592;            // total 744095744

// -------- merged prep: cast x->fp16 [0,2048) + weight transpose [2048,10240)
__global__ __launch_bounds__(256) void k_prep(
    const float* __restrict__ x, unsigned short* __restrict__ xb, int n8,
    const float* __restrict__ Wqkv, const float* __restrict__ Wkv,
    const float* __restrict__ Wq,   const float* __restrict__ Wpn,
    const float* __restrict__ Wpa,
    unsigned short* __restrict__ Tqkv, unsigned short* __restrict__ Tkv,
    unsigned short* __restrict__ Tq,   unsigned short* __restrict__ Tpn,
    unsigned short* __restrict__ Tpa) {
  int bxg = blockIdx.x;
  if (bxg < 2048) {                       // ---- cast (grid-stride, 32B/iter)
    int stride = 2048 * 256;
    for (int i = bxg * 256 + threadIdx.x; i < n8; i += stride) {
      float4 v0 = ((const float4*)x)[i * 2];
      float4 v1 = ((const float4*)x)[i * 2 + 1];
      uint4 w;
      w.x = (unsigned)f2h(v0.x) | ((unsigned)f2h(v0.y) << 16);
      w.y = (unsigned)f2h(v0.z) | ((unsigned)f2h(v0.w) << 16);
      w.z = (unsigned)f2h(v1.x) | ((unsigned)f2h(v1.y) << 16);
      w.w = (unsigned)f2h(v1.z) | ((unsigned)f2h(v1.w) << 16);
      ((uint4*)xb)[i] = w;
    }
    return;
  }
  // ---- weight transpose+cast (5 weights, flattened 256 x 32 grid)
  __shared__ float ts[32][33];
  int bx2 = bxg - 2048;
  int bx = bx2 & 255, ky = bx2 >> 8;
  const float* W; unsigned short* Wt; int Nc, nb;
  if (bx < 96)       { W = Wqkv; Wt = Tqkv; Nc = 3072; nb = bx; }
  else if (bx < 160) { W = Wkv;  Wt = Tkv;  Nc = 2048; nb = bx - 96; }
  else if (bx < 192) { W = Wq;   Wt = Tq;   Nc = 1024; nb = bx - 160; }
  else if (bx < 224) { W = Wpn;  Wt = Tpn;  Nc = 1024; nb = bx - 192; }
  else               { W = Wpa;  Wt = Tpa;  Nc = 1024; nb = bx - 224; }
  int n0 = nb * 32, k0 = ky * 32;
  int tx = threadIdx.x & 31, ty = threadIdx.x >> 5;   // 32 x 8
#pragma unroll
  for (int i = 0; i < 4; i++) {
    int k = ty + i * 8;
    ts[k][tx] = W[(size_t)(k0 + k) * Nc + n0 + tx];
  }
  __syncthreads();
#pragma unroll
  for (int i = 0; i < 4; i++) {
    int n = ty + i * 8;
    Wt[(size_t)(n0 + n) * 1024 + k0 + tx] = f2h(ts[tx][n]);
  }
}

// ======== 256x256 8-phase pipelined GEMM body, BK=32, 64KB LDS =============
// K=1024 -> 32 K-tiles, 16 iterations x 8 phases (2 K-tiles/iter).
// LDS dbuf d (32KB each): A chunks a0,a1 (8KB, rows rho=(rc>>6)*128+a*64+
// (rc&63), 64B/row); B at +16KB, chunks b0,b1 (n=((rc>>5)&3)*64+b*32+(rc&31)).
// k-chunk swizzle sigma_r(c) = c ^ ((r>>1)&3), inverse on global source.
// Stage = 1 gload_lds/thread. vmcnt(3) at p4/p8 (confirms next tile's 4
// chunks); prologue 7 stages -> vmcnt(3) confirms t0. Barriers: 6/iter.
template <int EPI>
__device__ __forceinline__ void gemm256_body(
    const unsigned short* __restrict__ A, const unsigned short* __restrict__ Bt,
    const float* __restrict__ bias, void* __restrict__ outp,
    int M, int NTN, int arpb, int aoff, int ldo, int orpb, int ooff,
    int wg, char* lds) {
  int tid = threadIdx.x, lane = tid & 63, wid = tid >> 6;
  int fr = lane & 15, fg = lane >> 4;

  int mt = wg / NTN, nt = wg - mt * NTN;
  int r0 = mt << 8, n0 = nt << 8;
  if (r0 > M - 256) r0 = M - 256;                    // overlap tile

  // ---- staging source pointers (1 gload_lds per chunk-stage per thread) ----
  int rc = tid >> 2;                                 // chunk-local row 0..127
  int cc = (tid & 3) ^ ((rc >> 1) & 3);              // inverse-swizzled chunk
  const unsigned short* pA[2];
  const unsigned short* pB[2];
#pragma unroll
  for (int a = 0; a < 2; a++) {
    int row = (rc >> 6) * 128 + a * 64 + (rc & 63);
    int r = r0 + row;
    if (r >= M) r = M - 1;
    size_t gr;
    if (arpb > 0) { int bb = r / arpb; gr = (size_t)bb * 825 + aoff + (r - bb * arpb); }
    else gr = (size_t)r;
    pA[a] = A + gr * 1024 + cc * 8;
  }
#pragma unroll
  for (int b = 0; b < 2; b++) {
    int n = ((rc >> 5) & 3) * 64 + b * 32 + (rc & 31);
    pB[b] = Bt + (size_t)(n0 + n) * 1024 + cc * 8;
  }

  int wr = wid >> 2, wc = wid & 3;                   // 2(M) x 4(N) waves
  int ch0 = fg ^ ((fr >> 1) & 3);
  int aoff0 = (wr * 64 + fr) * 64 + ch0 * 16;
  int boff0 = (wc * 32 + fr) * 64 + ch0 * 16;

  u16x8 afr[4], bf0[2], bf1[2];
  f32x4 acc[8][4] = {};

#define BAR  asm volatile("s_barrier" ::: "memory")
#define VM3  asm volatile("s_waitcnt vmcnt(3)" ::: "memory")
#define VM0  asm volatile("s_waitcnt vmcnt(0)" ::: "memory")

  auto LDA = [&](int d, int a) {                     // 4 x ds_read_b128
    char* base = lds + d * 32768 + a * 8192;
#pragma unroll
    for (int mm = 0; mm < 4; mm++)
      afr[mm] = *(const u16x8*)(base + mm * 1024 + aoff0);
  };
  auto LDB = [&](int d, int b, u16x8* bf) {          // 2 x ds_read_b128
    char* base = lds + d * 32768 + 16384 + b * 8192;
#pragma unroll
    for (int nn = 0; nn < 2; nn++)
      bf[nn] = *(const u16x8*)(base + nn * 1024 + boff0);
  };
  auto STAGE_A = [&](int d, int a, int t) {
    async16(lds + d * 32768 + a * 8192 + (wid << 10), pA[a] + t * 32);
  };
  auto STAGE_B = [&](int d, int b, int t) {
    async16(lds + d * 32768 + 16384 + b * 8192 + (wid << 10), pB[b] + t * 32);
  };
  auto CLUSTER = [&](int a, int b, u16x8* bf) {      // 8 MFMA, one C-quadrant
    __builtin_amdgcn_s_setprio(1);
#pragma unroll
    for (int mm = 0; mm < 4; mm++)
#pragma unroll
      for (int nn = 0; nn < 2; nn++)
        mfma16(acc[a * 4 + mm][b * 2 + nn], afr[mm], bf[nn]);
    __builtin_amdgcn_s_setprio(0);
  };

  // ---- prologue: t0 all 4 chunks + t1 first 3, confirm t0 ----
  STAGE_A(0, 0, 0); STAGE_B(0, 0, 0); STAGE_B(0, 1, 0); STAGE_A(0, 1, 0);
  STAGE_A(1, 0, 1); STAGE_B(1, 0, 1); STAGE_B(1, 1, 1);
  VM3; BAR;

#pragma unroll 1
  for (int i = 0; i < 16; i++) {
    bool nl = (i < 15);
    int t1 = 2 * i + 1, t2 = 2 * i + 2, t3 = 2 * i + 3;
    // p1
    LDA(0, 0); LDB(0, 0, bf0);
    STAGE_A(1, 1, t1);
    CLUSTER(0, 0, bf0); BAR;
    // p2 (no end barrier)
    LDB(0, 1, bf1);
    if (nl) STAGE_A(0, 0, t2);
    CLUSTER(0, 1, bf1);
    // p3
    LDA(0, 1);
    if (nl) STAGE_B(0, 0, t2);
    CLUSTER(1, 0, bf0); BAR;
    // p4
    if (nl) STAGE_B(0, 1, t2);
    CLUSTER(1, 1, bf1);
    if (nl) { VM3; } else { VM0; }
    BAR;
    // p5
    LDA(1, 0); LDB(1, 0, bf0);
    if (nl) STAGE_A(0, 1, t2);
    CLUSTER(0, 0, bf0); BAR;
    // p6 (no end barrier)
    LDB(1, 1, bf1);
    if (nl) STAGE_A(1, 0, t3);
    CLUSTER(0, 1, bf1);
    // p7
    LDA(1, 1);
    if (nl) STAGE_B(1, 0, t3);
    CLUSTER(1, 0, bf0); BAR;
    // p8
    if (nl) STAGE_B(1, 1, t3);
    CLUSTER(1, 1, bf1);
    if (nl) { VM3; } else { VM0; }
    BAR;
  }
#undef BAR
#undef VM3
#undef VM0

  // ---- epilogue (BK-independent) ----
  int coln[4];
#pragma unroll
  for (int n = 0; n < 4; n++)
    coln[n] = n0 + wc * 64 + (n >> 1) * 32 + (n & 1) * 16 + fr;
  if (EPI == 0) {
    unsigned short* o = (unsigned short*)outp;
#pragma unroll
    for (int m = 0; m < 8; m++)
#pragma unroll
      for (int reg = 0; reg < 4; reg++) {
        int r = r0 + wr * 128 + (m >> 2) * 64 + (m & 3) * 16 + (lane >> 4) * 4 + reg;
        if (r < M) {
          size_t base = (size_t)r * ldo;
#pragma unroll
          for (int n = 0; n < 4; n++) o[base + coln[n]] = f2h(acc[m][n][reg]);
        }
      }
  } else {
    float* o = (float*)outp;
#pragma unroll
    for (int m = 0; m < 8; m++)
#pragma unroll
      for (int reg = 0; reg < 4; reg++) {
        int r = r0 + wr * 128 + (m >> 2) * 64 + (m & 3) * 16 + (lane >> 4) * 4 + reg;
        if (r < M) {
          int bb = r / orpb;
          size_t orow = (size_t)bb * 825 + ooff + (r - bb * orpb);
          size_t base = orow * 1024;
#pragma unroll
          for (int n = 0; n < 4; n++)
            o[base + coln[n]] = acc[m][n][reg] + bias[coln[n]];
        }
      }
  }
}

// ---- merged input GEMMs: qkv [0,2304) + kv [2304,3848) + q_act [3848,3908)
__global__ __launch_bounds__(512, 2) void k_gemm_in(
    const unsigned short* __restrict__ xb,
    const unsigned short* __restrict__ WtQKV,
    const unsigned short* __restrict__ WtKV,
    const unsigned short* __restrict__ WtQ,
    unsigned short* __restrict__ qkv, unsigned short* __restrict__ kvb,
    unsigned short* __restrict__ qact) {
  extern __shared__ char lds[];
  int bid = blockIdx.x;
  if (bid < 2304) {
    gemm256_body<0>(xb, WtQKV, nullptr, qkv, 49152, 12, 768, 57, 3072, 0, 0,
                    xcd_swz(bid, 2304), lds);
  } else if (bid < 3848) {
    gemm256_body<0>(xb, WtKV, nullptr, kvb, 49216, 8, 769, 56, 2048, 0, 0,
                    xcd_swz(bid - 2304, 1544), lds);
  } else {
    gemm256_body<0>(xb, WtQ, nullptr, qact, 3648, 4, 57, 0, 1024, 0, 0,
                    xcd_swz(bid - 3848, 60), lds);
  }
}

// ---- standalone 256x256 GEMM (proj_non, EPI=1) ----
template <int EPI>
__global__ __launch_bounds__(512, 2) void k_gemm256(
    const unsigned short* __restrict__ A, const unsigned short* __restrict__ Bt,
    const float* __restrict__ bias, void* __restrict__ outp,
    int M, int NTN, int arpb, int aoff, int ldo, int orpb, int ooff) {
  extern __shared__ char lds[];
  gemm256_body<EPI>(A, Bt, bias, outp, M, NTN, arpb, aoff, ldo, orpb, ooff,
                    xcd_swz(blockIdx.x, gridDim.x), lds);
}

// ---------------- 128x128 fp16 GEMM (proj_act) --------
template <int EPI>
__global__ __launch_bounds__(256, 2) void k_gemm(
    const unsigned short* __restrict__ A, const unsigned short* __restrict__ Bt,
    const float* __restrict__ bias, void* __restrict__ outp,
    int M, int Nn, int arpb, int aoff, int ldo, int orpb, int ooff) {
  __shared__ __align__(16) unsigned short As[128 * 32];
  __shared__ __align__(16) unsigned short Bs[128 * 32];
  int tid = threadIdx.x, lane = tid & 63, wid = tid >> 6;
  int NT = Nn >> 7;
  int mt = blockIdx.x / NT, nt = blockIdx.x - mt * NT;
  int r0 = mt << 7, n0 = nt << 7;

  const unsigned short* aptr[2];
  const unsigned short* bptr[2];
#pragma unroll
  for (int i = 0; i < 2; i++) {
    int c = tid + (i << 8);
    int r = r0 + (c >> 2);
    if (r >= M) r = M - 1;
    size_t gr;
    if (arpb > 0) { int bb = r / arpb; gr = (size_t)bb * 825 + aoff + (r - bb * arpb); }
    else gr = (size_t)r;
    aptr[i] = A + gr * 1024 + (c & 3) * 8;
    bptr[i] = Bt + (size_t)(n0 + (c >> 2)) * 1024 + (c & 3) * 8;
  }
  char* AsB = (char*)As;
  char* BsB = (char*)Bs;
  int wr = wid >> 1, wc = wid & 1;
  int fr = lane & 15, fcol = (lane >> 4) * 16;
  f32x4 acc[4][4] = {};

  for (int kk = 0; kk < 1024; kk += 32) {
    async16(AsB + (wid << 10), aptr[0] + kk);
    async16(AsB + 4096 + (wid << 10), aptr[1] + kk);
    async16(BsB + (wid << 10), bptr[0] + kk);
    async16(BsB + 4096 + (wid << 10), bptr[1] + kk);
    __syncthreads();
    u16x8 af[4], bfv[4];
#pragma unroll
    for (int m = 0; m < 4; m++)
      af[m] = *(const u16x8*)(AsB + (wr * 64 + m * 16 + fr) * 64 + fcol);
#pragma unroll
    for (int n = 0; n < 4; n++)
      bfv[n] = *(const u16x8*)(BsB + (wc * 64 + n * 16 + fr) * 64 + fcol);
#pragma unroll
    for (int m = 0; m < 4; m++)
#pragma unroll
      for (int n = 0; n < 4; n++) mfma16(acc[m][n], af[m], bfv[n]);
    __syncthreads();
  }

  int cb = wc * 64 + fr;
  int rb = wr * 64 + (lane >> 4) * 4;
  if (EPI == 0) {
    unsigned short* o = (unsigned short*)outp;
#pragma unroll
    for (int m = 0; m < 4; m++)
#pragma unroll
      for (int reg = 0; reg < 4; reg++) {
        int r = r0 + rb + m * 16 + reg;
        if (r < M) {
          size_t base = (size_t)r * ldo + n0 + cb;
#pragma unroll
          for (int n = 0; n < 4; n++) o[base + n * 16] = f2h(acc[m][n][reg]);
        }
      }
  } else {
    float* o = (float*)outp;
#pragma unroll
    for (int m = 0; m < 4; m++)
#pragma unroll
      for (int reg = 0; reg < 4; reg++) {
        int r = r0 + rb + m * 16 + reg;
        if (r < M) {
          int bb = r / orpb;
          size_t orow = (size_t)bb * 825 + ooff + (r - bb * orpb);
          size_t base = orow * 1024 + n0 + cb;
#pragma unroll
          for (int n = 0; n < 4; n++)
            o[base + n * 16] = acc[m][n][reg] + bias[n0 + cb + n * 16];
        }
      }
  }
}

// ================= attention bodies (merged kernel, r12 frozen) ============
static constexpr float C1 = 0.125f * 1.44269504089f;      // scale * log2(e)

__device__ __forceinline__ void attn_non_body(
    const unsigned short* __restrict__ qkv, unsigned short* __restrict__ aout,
    int bid, char* smem) {
  int h = bid & 15, t = bid >> 4;
  int g = t % 3, b = t / 3;
  int tid = threadIdx.x, lane = tid & 63, wid = tid >> 6;
  int fr = lane & 15, fg = lane >> 4;
  size_t rowbase = (size_t)(b * 768 + g * 256);
  const unsigned short* Qb = qkv + rowbase * 3072 + h * 64;
  const unsigned short* Kb = Qb + 1024;
  const unsigned short* Vb = Qb + 2048;

  char* Vt0 = smem;                    // [2][64*64] fp16 dbuf
  char* Pw = smem + 16384 + wid * 8192;

  int qr = wid * 64;
  u16x8 qf[4][2];
#pragma unroll
  for (int mq = 0; mq < 4; mq++)
#pragma unroll
    for (int ks = 0; ks < 2; ks++)
      qf[mq][ks] = *(const u16x8*)(Qb + (size_t)(qr + mq * 16 + fr) * 3072 + ks * 32 + fg * 8);

  f32x4 o[4][4] = {};
  float mrun[4], lrun[4];
#pragma unroll
  for (int mq = 0; mq < 4; mq++) { mrun[mq] = -1e30f; lrun[mq] = 0.f; }

  int vpr = lane & 31;                 // 2-way-bank V staging coords
  int vcc = wid * 2 + (lane >> 5);
  const unsigned short* Vp = Vb + (size_t)(2 * vpr) * 3072 + vcc * 8;

  u16x8 v0 = *(const u16x8*)(Vp);
  u16x8 v1 = *(const u16x8*)(Vp + 3072);
  u16x8 kf[2][4];
#pragma unroll
  for (int kt = 0; kt < 4; kt++)
#pragma unroll
    for (int ks = 0; ks < 2; ks++)
      kf[ks][kt] = *(const u16x8*)(Kb + (size_t)(kt * 16 + fr) * 3072 + ks * 32 + fg * 8);

  {                                    // prologue: write Vt[0]; prefetch c1
#pragma unroll
    for (int j = 0; j < 8; j++) {
      unsigned pk = (unsigned)v0[j] | ((unsigned)v1[j] << 16);
      *(unsigned*)(Vt0 + swz(vcc * 8 + j, 4 * vpr)) = pk;
    }
    v0 = *(const u16x8*)(Vp + (size_t)64 * 3072);
    v1 = *(const u16x8*)(Vp + (size_t)65 * 3072);
  }

  for (int c = 0; c < 4; c++) {
    __syncthreads();                   // Vt[c&1] written by all; PV(c-1) done
    if (c < 3) {                       // write Vt[(c+1)&1] from regs
      char* VtN = Vt0 + ((c + 1) & 1) * 8192;
#pragma unroll
      for (int j = 0; j < 8; j++) {
        unsigned pk = (unsigned)v0[j] | ((unsigned)v1[j] << 16);
        *(unsigned*)(VtN + swz(vcc * 8 + j, 4 * vpr)) = pk;
      }
      if (c < 2) {
        v0 = *(const u16x8*)(Vp + (size_t)(c + 2) * 64 * 3072);
        v1 = *(const u16x8*)(Vp + (size_t)((c + 2) * 64 + 1) * 3072);
      }
    }

    f32x4 s[4][4] = {};                // RAW S^T [key-tile][q-tile]
#pragma unroll
    for (int ks = 0; ks < 2; ks++)
#pragma unroll
      for (int kt = 0; kt < 4; kt++)
#pragma unroll
        for (int mq = 0; mq < 4; mq++) mfma16(s[kt][mq], kf[ks][kt], qf[mq][ks]);
    if (c < 3) {                       // prefetch next K (lands under SM+PV)
#pragma unroll
      for (int kt = 0; kt < 4; kt++)
#pragma unroll
        for (int ks = 0; ks < 2; ks++)
          kf[ks][kt] = *(const u16x8*)(Kb + (size_t)((c + 1) * 64 + kt * 16 + fr) * 3072 + ks * 32 + fg * 8);
    }

#pragma unroll
    for (int mq = 0; mq < 4; mq++) {
      float v = -1e30f;
#pragma unroll
      for (int kt = 0; kt < 4; kt++)
#pragma unroll
        for (int reg = 0; reg < 4; reg++) v = fmaxf(v, s[kt][mq][reg]);
      v = fmaxf(v, __shfl_xor(v, 16));
      v = fmaxf(v, __shfl_xor(v, 32));
      v *= C1;
      if (!__all(v <= mrun[mq] + 8.f)) {          // T13 defer-max
        float mn = fmaxf(mrun[mq], v);
        float alpha = exp2r(mrun[mq] - mn);
        mrun[mq] = mn;
        lrun[mq] *= alpha;
#pragma unroll
        for (int dt = 0; dt < 4; dt++) o[dt][mq] *= alpha;
      }
      float mn = mrun[mq];
      int q = mq * 16 + fr;
      float rs = 0.f;
#pragma unroll
      for (int kt = 0; kt < 4; kt++) {
        f32x4 p;
#pragma unroll
        for (int reg = 0; reg < 4; reg++)
          p[reg] = exp2r(fmaf(s[kt][mq][reg], C1, -mn));
        rs += p[0] + p[1] + p[2] + p[3];
        uint2 w;
        w.x = (unsigned)f2h(p[0]) | ((unsigned)f2h(p[1]) << 16);
        w.y = (unsigned)f2h(p[2]) | ((unsigned)f2h(p[3]) << 16);
        *(uint2*)(Pw + swz(q, kt * 32 + fg * 8)) = w;
      }
      rs += __shfl_xor(rs, 16);
      rs += __shfl_xor(rs, 32);
      lrun[mq] += rs;
    }
    char* VtB = Vt0 + (c & 1) * 8192;
#pragma unroll
    for (int ks = 0; ks < 2; ks++) {
      u16x8 vf[4], pf[4];
#pragma unroll
      for (int dt = 0; dt < 4; dt++)
        vf[dt] = *(const u16x8*)(VtB + swz(dt * 16 + fr, ks * 64 + fg * 16));
#pragma unroll
      for (int mq = 0; mq < 4; mq++)
        pf[mq] = *(const u16x8*)(Pw + swz(mq * 16 + fr, ks * 64 + fg * 16));
#pragma unroll
      for (int dt = 0; dt < 4; dt++)
#pragma unroll
        for (int mq = 0; mq < 4; mq++) mfma16(o[dt][mq], vf[dt], pf[mq]);
    }
  }

#pragma unroll
  for (int mq = 0; mq < 4; mq++) {
    float rl = 1.0f / lrun[mq];
    size_t row = rowbase + qr + mq * 16 + fr;
#pragma unroll
    for (int dt = 0; dt < 4; dt++) {
      uint2 w;
      w.x = (unsigned)f2h(o[dt][mq][0] * rl) | ((unsigned)f2h(o[dt][mq][1] * rl) << 16);
      w.y = (unsigned)f2h(o[dt][mq][2] * rl) | ((unsigned)f2h(o[dt][mq][3] * rl) << 16);
      *(uint2*)(aout + row * 1024 + h * 64 + dt * 16 + fg * 4) = w;
    }
  }
}

__device__ __forceinline__ void attn_act_body(
    const unsigned short* __restrict__ qa, const unsigned short* __restrict__ kv,
    unsigned short* __restrict__ aout, int bid, char* smem) {
  int h = bid & 15, b = bid >> 4;
  int tid = threadIdx.x, lane = tid & 63, wid = tid >> 6;
  int fr = lane & 15, fg = lane >> 4;
  const unsigned short* Qb = qa + (size_t)b * 57 * 1024 + h * 64;
  const unsigned short* Kb = kv + (size_t)b * 769 * 2048 + h * 64;
  const unsigned short* Vb = Kb + 1024;

  char* Vw = smem + wid * 8192;                 // [4][64*64]
  char* Pw = smem + 32768 + wid * 8192;         // [4][64*64]
  float* Ml = (float*)(smem + 65536);           // [4][64]
  float* Ll = (float*)(smem + 65536 + 1024);    // [4][64]

  u16x8 qf[4][2];
#pragma unroll
  for (int mq = 0; mq < 4; mq++) {
    int q = mq * 16 + fr;
    if (q > 56) q = 56;
#pragma unroll
    for (int ks = 0; ks < 2; ks++)
      qf[mq][ks] = *(const u16x8*)(Qb + (size_t)q * 1024 + ks * 32 + fg * 8);
  }
  f32x4 o[4][4] = {};
  float mrun[4], lrun[4];
#pragma unroll
  for (int mq = 0; mq < 4; mq++) { mrun[mq] = -1e30f; lrun[mq] = 0.f; }

  u16x8 kf[2][4];
  {                                            // preload K for first chunk
    int kc0 = wid * 64;
#pragma unroll
    for (int kt = 0; kt < 4; kt++) {
      int krow = kc0 + kt * 16 + fr;
      if (krow > 768) krow = 768;
#pragma unroll
      for (int ks = 0; ks < 2; ks++)
        kf[ks][kt] = *(const u16x8*)(Kb + (size_t)krow * 2048 + ks * 32 + fg * 8);
    }
  }

  int vpr = lane & 31;                         // 2-way-bank V staging coords
  for (int c = wid; c < 13; c += 4) {
    int kc0 = c * 64;
#pragma unroll
    for (int i = 0; i < 4; i++) {              // V^T staging (pair-packed b32)
      int cv = i * 2 + (lane >> 5);
      int kr0 = kc0 + 2 * vpr, kr1 = kc0 + 2 * vpr + 1;
      if (kr0 > 768) kr0 = 768;
      if (kr1 > 768) kr1 = 768;
      u16x8 v0 = *(const u16x8*)(Vb + (size_t)kr0 * 2048 + cv * 8);
      u16x8 v1 = *(const u16x8*)(Vb + (size_t)kr1 * 2048 + cv * 8);
#pragma unroll
      for (int j = 0; j < 8; j++) {
        unsigned pk = (unsigned)v0[j] | ((unsigned)v1[j] << 16);
        *(unsigned*)(Vw + swz(cv * 8 + j, 4 * vpr)) = pk;
      }
    }

    f32x4 s[4][4] = {};                        // RAW S^T
#pragma unroll
    for (int ks = 0; ks < 2; ks++)
#pragma unroll
      for (int kt = 0; kt < 4; kt++)
#pragma unroll
        for (int mq = 0; mq < 4; mq++) mfma16(s[kt][mq], kf[ks][kt], qf[mq][ks]);
    if (c + 4 < 13) {                          // prefetch next chunk's K
      int kn = (c + 4) * 64;
#pragma unroll
      for (int kt = 0; kt < 4; kt++) {
        int krow = kn + kt * 16 + fr;
        if (krow > 768) krow = 768;
#pragma unroll
        for (int ks = 0; ks < 2; ks++)
          kf[ks][kt] = *(const u16x8*)(Kb + (size_t)krow * 2048 + ks * 32 + fg * 8);
      }
    }
    if (kc0 + 64 > 769) {                      // mask invalid keys
#pragma unroll
      for (int kt = 0; kt < 4; kt++)
#pragma unroll
        for (int reg = 0; reg < 4; reg++)
          if (kc0 + kt * 16 + fg * 4 + reg >= 769)
#pragma unroll
            for (int mq = 0; mq < 4; mq++) s[kt][mq][reg] = -1e30f;
    }

#pragma unroll
    for (int mq = 0; mq < 4; mq++) {
      float v = -1e30f;
#pragma unroll
      for (int kt = 0; kt < 4; kt++)
#pragma unroll
        for (int reg = 0; reg < 4; reg++) v = fmaxf(v, s[kt][mq][reg]);
      v = fmaxf(v, __shfl_xor(v, 16));
      v = fmaxf(v, __shfl_xor(v, 32));
      v *= C1;
      if (!__all(v <= mrun[mq] + 8.f)) {       // T13 defer-max
        float mn = fmaxf(mrun[mq], v);
        float alpha = exp2r(mrun[mq] - mn);
        mrun[mq] = mn;
        lrun[mq] *= alpha;
#pragma unroll
        for (int dt = 0; dt < 4; dt++) o[dt][mq] *= alpha;
      }
      float mn = mrun[mq];
      int q = mq * 16 + fr;
      float rs = 0.f;
#pragma unroll
      for (int kt = 0; kt < 4; kt++) {
        f32x4 p;
#pragma unroll
        for (int reg = 0; reg < 4; reg++)
          p[reg] = exp2r(fmaf(s[kt][mq][reg], C1, -mn));
        rs += p[0] + p[1] + p[2] + p[3];
        uint2 w;
        w.x = (unsigned)f2h(p[0]) | ((unsigned)f2h(p[1]) << 16);
        w.y = (unsigned)f2h(p[2]) | ((unsigned)f2h(p[3]) << 16);
        *(uint2*)(Pw + swz(q, kt * 32 + fg * 8)) = w;
      }
      rs += __shfl_xor(rs, 16);
      rs += __shfl_xor(rs, 32);
      lrun[mq] += rs;
    }
#pragma unroll
    for (int ks = 0; ks < 2; ks++) {
      u16x8 vf[4], pf[4];
#pragma unroll
      for (int dt = 0; dt < 4; dt++)
        vf[dt] = *(const u16x8*)(Vw + swz(dt * 16 + fr, ks * 64 + fg * 16));
#pragma unroll
      for (int mq = 0; mq < 4; mq++)
        pf[mq] = *(const u16x8*)(Pw + swz(mq * 16 + fr, ks * 64 + fg * 16));
#pragma unroll
      for (int dt = 0; dt < 4; dt++)
#pragma unroll
        for (int mq = 0; mq < 4; mq++) mfma16(o[dt][mq], vf[dt], pf[mq]);
    }
  }

  // ---- combine wave partials (flash merge) ----
  __syncthreads();
  if (fg == 0) {
#pragma unroll
    for (int mq = 0; mq < 4; mq++) {
      Ml[wid * 64 + mq * 16 + fr] = mrun[mq];
      Ll[wid * 64 + mq * 16 + fr] = lrun[mq];
    }
  }
  __syncthreads();
  float* Oac = (float*)smem;                   // 16KB scratch over Vt[0..1]
  for (int i = tid; i < 4096; i += 256) Oac[i] = 0.f;
  __syncthreads();
  for (int w = 0; w < 4; w++) {
    if (wid == w) {
#pragma unroll
      for (int mq = 0; mq < 4; mq++) {
        int q = mq * 16 + fr;
        float Mq = fmaxf(fmaxf(Ml[q], Ml[64 + q]), fmaxf(Ml[128 + q], Ml[192 + q]));
        float f = exp2r(mrun[mq] - Mq);
#pragma unroll
        for (int dt = 0; dt < 4; dt++) {
          int d = dt * 16 + fg * 4;
#pragma unroll
          for (int reg = 0; reg < 4; reg++)
            Oac[(d + reg) * 64 + q] += o[dt][mq][reg] * f;
        }
      }
    }
    __syncthreads();
  }
  for (int i = tid; i < 4096; i += 256) {
    int d = i >> 6, q = i & 63;
    if (q < 57) {
      float Mq = fmaxf(fmaxf(Ml[q], Ml[64 + q]), fmaxf(Ml[128 + q], Ml[192 + q]));
      float Lq = Ll[q] * exp2r(Ml[q] - Mq) + Ll[64 + q] * exp2r(Ml[64 + q] - Mq) +
                 Ll[128 + q] * exp2r(Ml[128 + q] - Mq) + Ll[192 + q] * exp2r(Ml[192 + q] - Mq);
      aout[(size_t)(b * 57 + q) * 1024 + h * 64 + d] = f2h(Oac[i] / Lq);
    }
  }
}

// ---- merged attention: act [0,1024) first, non [1024,4096)
__global__ __launch_bounds__(256, 2) void k_attn(
    const unsigned short* __restrict__ qkv, const unsigned short* __restrict__ qa,
    const unsigned short* __restrict__ kv,
    unsigned short* __restrict__ anon, unsigned short* __restrict__ aact) {
  extern __shared__ char smem[];
  int bid = blockIdx.x;
  if (bid < 1024) attn_act_body(qa, kv, aact, bid, smem);
  else            attn_non_body(qkv, anon, bid - 1024, smem);
}

// ---------------------------------------------------------------------------
extern "C" void kernel_launch(void* const* d_in, const int* in_sizes, int n_in,
                              void* d_out, int out_size, void* d_ws, size_t ws_size,
                              hipStream_t stream) {
  const float* x    = (const float*)d_in[0];
  const float* Wqkv = (const float*)d_in[1];
  const float* Wq   = (const float*)d_in[2];
  const float* Wkv  = (const float*)d_in[3];
  const float* Wpn  = (const float*)d_in[4];
  const float* bpn  = (const float*)d_in[5];
  const float* Wpa  = (const float*)d_in[6];
  const float* bpa  = (const float*)d_in[7];
  float* out = (float*)d_out;
  char* ws = (char*)d_ws;

  unsigned short* xb   = (unsigned short*)(ws + OFF_XB);
  unsigned short* qkv  = (unsigned short*)(ws + OFF_QKV);
  unsigned short* kvb  = (unsigned short*)(ws + OFF_KV);
  unsigned short* qact = (unsigned short*)(ws + OFF_QACT);
  unsigned short* anon = (unsigned short*)(ws + OFF_ANON);
  unsigned short* aact = (unsigned short*)(ws + OFF_AACT);
  unsigned short* WtQKV = (unsigned short*)(ws + OFF_WQKV);
  unsigned short* WtKV  = (unsigned short*)(ws + OFF_WKV);
  unsigned short* WtQ   = (unsigned short*)(ws + OFF_WQ);
  unsigned short* WtPN  = (unsigned short*)(ws + OFF_WPN);
  unsigned short* WtPA  = (unsigned short*)(ws + OFF_WPA);

  hipFuncSetAttribute((const void*)k_gemm_in,
                      hipFuncAttributeMaxDynamicSharedMemorySize, 65536);
  hipFuncSetAttribute((const void*)k_gemm256<1>,
                      hipFuncAttributeMaxDynamicSharedMemorySize, 65536);
  hipFuncSetAttribute((const void*)k_attn,
                      hipFuncAttributeMaxDynamicSharedMemorySize, 67584);

  // prep: cast (blocks [0,2048)) + weight transpose ([2048,10240))
  k_prep<<<10240, 256, 0, stream>>>(x, xb, 6758400, Wqkv, Wkv, Wq, Wpn, Wpa,
                                    WtQKV, WtKV, WtQ, WtPN, WtPA);

  // ALL input GEMMs in one launch (qkv + kv + q_act; tail-wave backfill)
  k_gemm_in<<<3908, 512, 65536, stream>>>(xb, WtQKV, WtKV, WtQ,
                                          qkv, kvb, qact);

  // merged attention (act + non in one grid)
  k_attn<<<4096, 256, 67584, stream>>>(qkv, qact, kvb, anon, aact);

  // output projections (+bias)
  k_gemm256<1><<<192 * 4, 512, 65536, stream>>>(anon, WtPN, bpn, out,
                                                49152, 4, 0, 0, 1024, 768, 57);
  k_gemm<1><<<29 * 8, 256, 0, stream>>>(aact, WtPA, bpa, out,
                                        3648, 1024, 0, 0, 1024, 57, 0);
}

// Round 14
// 944.985 us; speedup vs baseline: 1.0587x; 1.0587x over previous
//
#include <hip/hip_runtime.h>
#include <stdint.h>

// ---------------------------------------------------------------------------
// SeparatedAttention on MI355X (gfx950), fp16 MFMA pipeline (fp32 accum).
// Round 14: RESTORE BEST. GEMM reverted to round-12 BK=64 8-phase/6-barrier
// (verified 525us gemm_in, 46% MfmaUtil, 0 conflicts; r13 BK=32 regressed
// 568us/42%). Keep r13's merged k_prep (cast+5x transpose, one launch) and
// r12's merged k_attn. This is the best verified configuration.
// ---------------------------------------------------------------------------

typedef __attribute__((ext_vector_type(8))) unsigned short u16x8;
typedef __attribute__((ext_vector_type(8))) _Float16 f16x8;
typedef __attribute__((ext_vector_type(4))) float f32x4;

__device__ __forceinline__ unsigned short f2h(float f) {   // RNE fp32->fp16
  _Float16 h = (_Float16)f;
  return __builtin_bit_cast(unsigned short, h);
}

__device__ __forceinline__ float exp2r(float x) {          // raw v_exp_f32
  return __builtin_amdgcn_exp2f(x);
}

__device__ __forceinline__ void mfma16(f32x4& d, u16x8 a, u16x8 b) {
  d = __builtin_amdgcn_mfma_f32_16x16x32_f16(
      __builtin_bit_cast(f16x8, a), __builtin_bit_cast(f16x8, b), d, 0, 0, 0);
}

// async global->LDS, 16B per lane; dest = wave-uniform base + lane*16
__device__ __forceinline__ void async16(void* lds_p, const void* g) {
  __builtin_amdgcn_global_load_lds(
      (const __attribute__((address_space(1))) unsigned int*)g,
      (__attribute__((address_space(3))) unsigned int*)lds_p, 16, 0, 0);
}

// XOR swizzle for [row][128B] LDS tiles (attention)
__device__ __forceinline__ int swz(int row, int bcol) {
  return (row << 7) + (bcol ^ ((row & 7) << 4));
}

// bijective XCD swizzle (m204)
__device__ __forceinline__ int xcd_swz(int bid, int nwg) {
  int q8 = nwg >> 3, r8 = nwg & 7;
  int xcd = bid & 7, idx = bid >> 3;
  return (xcd < r8 ? xcd * (q8 + 1) : r8 * (q8 + 1) + (xcd - r8) * q8) + idx;
}

// ---------------- workspace layout (bytes) ----------------
static constexpr size_t OFF_XB   = 0;                    // x fp16      108.1MB
static constexpr size_t OFF_QKV  = 108134400;            // qkv fp16    302.0MB
static constexpr size_t OFF_KV   = 410124288;            // kv fp16     201.6MB
static constexpr size_t OFF_QACT = 611713024;            // q_act fp16    7.5MB
static constexpr size_t OFF_ANON = 619184128;            // attn_non    100.7MB
static constexpr size_t OFF_AACT = 719847424;            // attn_act      7.5MB
static constexpr size_t OFF_WQKV = 727318528;            // W^T fp16 ...
static constexpr size_t OFF_WKV  = 733609984;
static constexpr size_t OFF_WQ   = 737804288;
static constexpr size_t OFF_WPN  = 739901440;
static constexpr size_t OFF_WPA  = 741998592;            // total 744095744

// -------- merged prep: cast x->fp16 [0,2048) + weight transpose [2048,10240)
__global__ __launch_bounds__(256) void k_prep(
    const float* __restrict__ x, unsigned short* __restrict__ xb, int n8,
    const float* __restrict__ Wqkv, const float* __restrict__ Wkv,
    const float* __restrict__ Wq,   const float* __restrict__ Wpn,
    const float* __restrict__ Wpa,
    unsigned short* __restrict__ Tqkv, unsigned short* __restrict__ Tkv,
    unsigned short* __restrict__ Tq,   unsigned short* __restrict__ Tpn,
    unsigned short* __restrict__ Tpa) {
  int bxg = blockIdx.x;
  if (bxg < 2048) {                       // ---- cast (grid-stride, 32B/iter)
    int stride = 2048 * 256;
    for (int i = bxg * 256 + threadIdx.x; i < n8; i += stride) {
      float4 v0 = ((const float4*)x)[i * 2];
      float4 v1 = ((const float4*)x)[i * 2 + 1];
      uint4 w;
      w.x = (unsigned)f2h(v0.x) | ((unsigned)f2h(v0.y) << 16);
      w.y = (unsigned)f2h(v0.z) | ((unsigned)f2h(v0.w) << 16);
      w.z = (unsigned)f2h(v1.x) | ((unsigned)f2h(v1.y) << 16);
      w.w = (unsigned)f2h(v1.z) | ((unsigned)f2h(v1.w) << 16);
      ((uint4*)xb)[i] = w;
    }
    return;
  }
  // ---- weight transpose+cast (5 weights, flattened 256 x 32 grid)
  __shared__ float ts[32][33];
  int bx2 = bxg - 2048;
  int bx = bx2 & 255, ky = bx2 >> 8;
  const float* W; unsigned short* Wt; int Nc, nb;
  if (bx < 96)       { W = Wqkv; Wt = Tqkv; Nc = 3072; nb = bx; }
  else if (bx < 160) { W = Wkv;  Wt = Tkv;  Nc = 2048; nb = bx - 96; }
  else if (bx < 192) { W = Wq;   Wt = Tq;   Nc = 1024; nb = bx - 160; }
  else if (bx < 224) { W = Wpn;  Wt = Tpn;  Nc = 1024; nb = bx - 192; }
  else               { W = Wpa;  Wt = Tpa;  Nc = 1024; nb = bx - 224; }
  int n0 = nb * 32, k0 = ky * 32;
  int tx = threadIdx.x & 31, ty = threadIdx.x >> 5;   // 32 x 8
#pragma unroll
  for (int i = 0; i < 4; i++) {
    int k = ty + i * 8;
    ts[k][tx] = W[(size_t)(k0 + k) * Nc + n0 + tx];
  }
  __syncthreads();
#pragma unroll
  for (int i = 0; i < 4; i++) {
    int n = ty + i * 8;
    Wt[(size_t)(n0 + n) * 1024 + k0 + tx] = f2h(ts[tx][n]);
  }
}

// ========== 256x256 8-phase pipelined GEMM body (r12-exact, BK=64) =========
// K=1024 -> 16 K-tiles, 8 iterations x 8 phases (2 K-tiles/iter).
// Barrier set (6/iter): end of p1,p3,p4(+vmcnt6),p5,p7,p8(+vmcnt6).
template <int EPI>
__device__ __forceinline__ void gemm256_body(
    const unsigned short* __restrict__ A, const unsigned short* __restrict__ Bt,
    const float* __restrict__ bias, void* __restrict__ outp,
    int M, int NTN, int arpb, int aoff, int ldo, int orpb, int ooff,
    int wg, char* lds) {
  int tid = threadIdx.x, lane = tid & 63, wid = tid >> 6;
  int fr = lane & 15, fg = lane >> 4;

  int mt = wg / NTN, nt = wg - mt * NTN;
  int r0 = mt << 8, n0 = nt << 8;
  if (r0 > M - 256) r0 = M - 256;                    // overlap tile

  const unsigned short* pA[2][2];   // [a][j]
  const unsigned short* pB[2][2];   // [b][j]
#pragma unroll
  for (int j = 0; j < 2; j++) {
    int rc = (wid * 2 + j) * 8 + (lane >> 3);        // rho within chunk 0..127
    int cc = (lane & 7) ^ (rc & 7);                  // inverse-swizzled chunk
#pragma unroll
    for (int a = 0; a < 2; a++) {
      int row = (rc >> 6) * 128 + a * 64 + (rc & 63);
      int r = r0 + row;
      if (r >= M) r = M - 1;
      size_t gr;
      if (arpb > 0) { int bb = r / arpb; gr = (size_t)bb * 825 + aoff + (r - bb * arpb); }
      else gr = (size_t)r;
      pA[a][j] = A + gr * 1024 + cc * 8;
    }
#pragma unroll
    for (int b = 0; b < 2; b++) {
      int n = ((rc >> 5) & 3) * 64 + b * 32 + (rc & 31);
      pB[b][j] = Bt + (size_t)(n0 + n) * 1024 + cc * 8;
    }
  }

  int wr = wid >> 2, wc = wid & 3;                   // 2(M) x 4(N) waves
  int ch0 = fg ^ (fr & 7);
  int aoff0 = (wr * 64 + fr) * 128 + ch0 * 16;
  int boff0 = (wc * 32 + fr) * 128 + ch0 * 16;

  u16x8 afr[8], bf0[4], bf1[4];
  f32x4 acc[8][4] = {};

#define BAR  asm volatile("s_barrier" ::: "memory")
#define VM6  asm volatile("s_waitcnt vmcnt(6)" ::: "memory")
#define VM0  asm volatile("s_waitcnt vmcnt(0)" ::: "memory")

  auto LDA = [&](int d, int a) {                     // 8 x ds_read_b128
    char* base = lds + d * 65536 + a * 16384;
#pragma unroll
    for (int mm = 0; mm < 4; mm++)
#pragma unroll
      for (int ks = 0; ks < 2; ks++)
        afr[mm * 2 + ks] = *(const u16x8*)(base + mm * 2048 + (aoff0 ^ (ks * 64)));
  };
  auto LDB = [&](int d, int b, u16x8* bf) {          // 4 x ds_read_b128
    char* base = lds + d * 65536 + 32768 + b * 16384;
#pragma unroll
    for (int nn = 0; nn < 2; nn++)
#pragma unroll
      for (int ks = 0; ks < 2; ks++)
        bf[nn * 2 + ks] = *(const u16x8*)(base + nn * 2048 + (boff0 ^ (ks * 64)));
  };
  auto STAGE_A = [&](int d, int a, int t) {
#pragma unroll
    for (int j = 0; j < 2; j++)
      async16(lds + d * 65536 + a * 16384 + ((wid * 2 + j) << 10), pA[a][j] + t * 64);
  };
  auto STAGE_B = [&](int d, int b, int t) {
#pragma unroll
    for (int j = 0; j < 2; j++)
      async16(lds + d * 65536 + 32768 + b * 16384 + ((wid * 2 + j) << 10), pB[b][j] + t * 64);
  };
  auto CLUSTER = [&](int a, int b, u16x8* bf) {      // 16 MFMA, one C-quadrant
    __builtin_amdgcn_s_setprio(1);
#pragma unroll
    for (int mm = 0; mm < 4; mm++)
#pragma unroll
      for (int nn = 0; nn < 2; nn++)
#pragma unroll
        for (int ks = 0; ks < 2; ks++)
          mfma16(acc[a * 4 + mm][b * 2 + nn], afr[mm * 2 + ks], bf[nn * 2 + ks]);
    __builtin_amdgcn_s_setprio(0);
  };

  STAGE_A(0, 0, 0); STAGE_B(0, 0, 0); STAGE_B(0, 1, 0); STAGE_A(0, 1, 0);
  STAGE_A(1, 0, 1); STAGE_B(1, 0, 1); STAGE_B(1, 1, 1);
  VM6; BAR;

#pragma unroll 1
  for (int i = 0; i < 8; i++) {
    bool nl = (i < 7);
    int t1 = 2 * i + 1, t2 = 2 * i + 2, t3 = 2 * i + 3;
    // p1
    LDA(0, 0); LDB(0, 0, bf0);
    STAGE_A(1, 1, t1);
    CLUSTER(0, 0, bf0); BAR;
    // p2 (no end barrier)
    LDB(0, 1, bf1);
    if (nl) STAGE_A(0, 0, t2);
    CLUSTER(0, 1, bf1);
    // p3
    LDA(0, 1);
    if (nl) STAGE_B(0, 0, t2);
    CLUSTER(1, 0, bf0); BAR;
    // p4
    if (nl) STAGE_B(0, 1, t2);
    CLUSTER(1, 1, bf1);
    if (nl) { VM6; } else { VM0; }
    BAR;
    // p5
    LDA(1, 0); LDB(1, 0, bf0);
    if (nl) STAGE_A(0, 1, t2);
    CLUSTER(0, 0, bf0); BAR;
    // p6 (no end barrier)
    LDB(1, 1, bf1);
    if (nl) STAGE_A(1, 0, t3);
    CLUSTER(0, 1, bf1);
    // p7
    LDA(1, 1);
    if (nl) STAGE_B(1, 0, t3);
    CLUSTER(1, 0, bf0); BAR;
    // p8
    if (nl) STAGE_B(1, 1, t3);
    CLUSTER(1, 1, bf1);
    if (nl) { VM6; } else { VM0; }
    BAR;
  }
#undef BAR
#undef VM6
#undef VM0

  // ---- epilogue ----
  int coln[4];
#pragma unroll
  for (int n = 0; n < 4; n++)
    coln[n] = n0 + wc * 64 + (n >> 1) * 32 + (n & 1) * 16 + fr;
  if (EPI == 0) {
    unsigned short* o = (unsigned short*)outp;
#pragma unroll
    for (int m = 0; m < 8; m++)
#pragma unroll
      for (int reg = 0; reg < 4; reg++) {
        int r = r0 + wr * 128 + (m >> 2) * 64 + (m & 3) * 16 + (lane >> 4) * 4 + reg;
        if (r < M) {
          size_t base = (size_t)r * ldo;
#pragma unroll
          for (int n = 0; n < 4; n++) o[base + coln[n]] = f2h(acc[m][n][reg]);
        }
      }
  } else {
    float* o = (float*)outp;
#pragma unroll
    for (int m = 0; m < 8; m++)
#pragma unroll
      for (int reg = 0; reg < 4; reg++) {
        int r = r0 + wr * 128 + (m >> 2) * 64 + (m & 3) * 16 + (lane >> 4) * 4 + reg;
        if (r < M) {
          int bb = r / orpb;
          size_t orow = (size_t)bb * 825 + ooff + (r - bb * orpb);
          size_t base = orow * 1024;
#pragma unroll
          for (int n = 0; n < 4; n++)
            o[base + coln[n]] = acc[m][n][reg] + bias[coln[n]];
        }
      }
  }
}

// ---- merged input GEMMs: qkv [0,2304) + kv [2304,3848) + q_act [3848,3908)
__global__ __launch_bounds__(512, 2) void k_gemm_in(
    const unsigned short* __restrict__ xb,
    const unsigned short* __restrict__ WtQKV,
    const unsigned short* __restrict__ WtKV,
    const unsigned short* __restrict__ WtQ,
    unsigned short* __restrict__ qkv, unsigned short* __restrict__ kvb,
    unsigned short* __restrict__ qact) {
  extern __shared__ char lds[];
  int bid = blockIdx.x;
  if (bid < 2304) {
    gemm256_body<0>(xb, WtQKV, nullptr, qkv, 49152, 12, 768, 57, 3072, 0, 0,
                    xcd_swz(bid, 2304), lds);
  } else if (bid < 3848) {
    gemm256_body<0>(xb, WtKV, nullptr, kvb, 49216, 8, 769, 56, 2048, 0, 0,
                    xcd_swz(bid - 2304, 1544), lds);
  } else {
    gemm256_body<0>(xb, WtQ, nullptr, qact, 3648, 4, 57, 0, 1024, 0, 0,
                    xcd_swz(bid - 3848, 60), lds);
  }
}

// ---- standalone 256x256 GEMM (proj_non, EPI=1) ----
template <int EPI>
__global__ __launch_bounds__(512, 2) void k_gemm256(
    const unsigned short* __restrict__ A, const unsigned short* __restrict__ Bt,
    const float* __restrict__ bias, void* __restrict__ outp,
    int M, int NTN, int arpb, int aoff, int ldo, int orpb, int ooff) {
  extern __shared__ char lds[];
  gemm256_body<EPI>(A, Bt, bias, outp, M, NTN, arpb, aoff, ldo, orpb, ooff,
                    xcd_swz(blockIdx.x, gridDim.x), lds);
}

// ---------------- 128x128 fp16 GEMM (proj_act) --------
template <int EPI>
__global__ __launch_bounds__(256, 2) void k_gemm(
    const unsigned short* __restrict__ A, const unsigned short* __restrict__ Bt,
    const float* __restrict__ bias, void* __restrict__ outp,
    int M, int Nn, int arpb, int aoff, int ldo, int orpb, int ooff) {
  __shared__ __align__(16) unsigned short As[128 * 32];
  __shared__ __align__(16) unsigned short Bs[128 * 32];
  int tid = threadIdx.x, lane = tid & 63, wid = tid >> 6;
  int NT = Nn >> 7;
  int mt = blockIdx.x / NT, nt = blockIdx.x - mt * NT;
  int r0 = mt << 7, n0 = nt << 7;

  const unsigned short* aptr[2];
  const unsigned short* bptr[2];
#pragma unroll
  for (int i = 0; i < 2; i++) {
    int c = tid + (i << 8);
    int r = r0 + (c >> 2);
    if (r >= M) r = M - 1;
    size_t gr;
    if (arpb > 0) { int bb = r / arpb; gr = (size_t)bb * 825 + aoff + (r - bb * arpb); }
    else gr = (size_t)r;
    aptr[i] = A + gr * 1024 + (c & 3) * 8;
    bptr[i] = Bt + (size_t)(n0 + (c >> 2)) * 1024 + (c & 3) * 8;
  }
  char* AsB = (char*)As;
  char* BsB = (char*)Bs;
  int wr = wid >> 1, wc = wid & 1;
  int fr = lane & 15, fcol = (lane >> 4) * 16;
  f32x4 acc[4][4] = {};

  for (int kk = 0; kk < 1024; kk += 32) {
    async16(AsB + (wid << 10), aptr[0] + kk);
    async16(AsB + 4096 + (wid << 10), aptr[1] + kk);
    async16(BsB + (wid << 10), bptr[0] + kk);
    async16(BsB + 4096 + (wid << 10), bptr[1] + kk);
    __syncthreads();
    u16x8 af[4], bfv[4];
#pragma unroll
    for (int m = 0; m < 4; m++)
      af[m] = *(const u16x8*)(AsB + (wr * 64 + m * 16 + fr) * 64 + fcol);
#pragma unroll
    for (int n = 0; n < 4; n++)
      bfv[n] = *(const u16x8*)(BsB + (wc * 64 + n * 16 + fr) * 64 + fcol);
#pragma unroll
    for (int m = 0; m < 4; m++)
#pragma unroll
      for (int n = 0; n < 4; n++) mfma16(acc[m][n], af[m], bfv[n]);
    __syncthreads();
  }

  int cb = wc * 64 + fr;
  int rb = wr * 64 + (lane >> 4) * 4;
  if (EPI == 0) {
    unsigned short* o = (unsigned short*)outp;
#pragma unroll
    for (int m = 0; m < 4; m++)
#pragma unroll
      for (int reg = 0; reg < 4; reg++) {
        int r = r0 + rb + m * 16 + reg;
        if (r < M) {
          size_t base = (size_t)r * ldo + n0 + cb;
#pragma unroll
          for (int n = 0; n < 4; n++) o[base + n * 16] = f2h(acc[m][n][reg]);
        }
      }
  } else {
    float* o = (float*)outp;
#pragma unroll
    for (int m = 0; m < 4; m++)
#pragma unroll
      for (int reg = 0; reg < 4; reg++) {
        int r = r0 + rb + m * 16 + reg;
        if (r < M) {
          int bb = r / orpb;
          size_t orow = (size_t)bb * 825 + ooff + (r - bb * orpb);
          size_t base = orow * 1024 + n0 + cb;
#pragma unroll
          for (int n = 0; n < 4; n++)
            o[base + n * 16] = acc[m][n][reg] + bias[n0 + cb + n * 16];
        }
      }
  }
}

// ================= attention bodies (merged kernel, r12 frozen) ============
static constexpr float C1 = 0.125f * 1.44269504089f;      // scale * log2(e)

__device__ __forceinline__ void attn_non_body(
    const unsigned short* __restrict__ qkv, unsigned short* __restrict__ aout,
    int bid, char* smem) {
  int h = bid & 15, t = bid >> 4;
  int g = t % 3, b = t / 3;
  int tid = threadIdx.x, lane = tid & 63, wid = tid >> 6;
  int fr = lane & 15, fg = lane >> 4;
  size_t rowbase = (size_t)(b * 768 + g * 256);
  const unsigned short* Qb = qkv + rowbase * 3072 + h * 64;
  const unsigned short* Kb = Qb + 1024;
  const unsigned short* Vb = Qb + 2048;

  char* Vt0 = smem;                    // [2][64*64] fp16 dbuf
  char* Pw = smem + 16384 + wid * 8192;

  int qr = wid * 64;
  u16x8 qf[4][2];
#pragma unroll
  for (int mq = 0; mq < 4; mq++)
#pragma unroll
    for (int ks = 0; ks < 2; ks++)
      qf[mq][ks] = *(const u16x8*)(Qb + (size_t)(qr + mq * 16 + fr) * 3072 + ks * 32 + fg * 8);

  f32x4 o[4][4] = {};
  float mrun[4], lrun[4];
#pragma unroll
  for (int mq = 0; mq < 4; mq++) { mrun[mq] = -1e30f; lrun[mq] = 0.f; }

  int vpr = lane & 31;                 // 2-way-bank V staging coords
  int vcc = wid * 2 + (lane >> 5);
  const unsigned short* Vp = Vb + (size_t)(2 * vpr) * 3072 + vcc * 8;

  u16x8 v0 = *(const u16x8*)(Vp);
  u16x8 v1 = *(const u16x8*)(Vp + 3072);
  u16x8 kf[2][4];
#pragma unroll
  for (int kt = 0; kt < 4; kt++)
#pragma unroll
    for (int ks = 0; ks < 2; ks++)
      kf[ks][kt] = *(const u16x8*)(Kb + (size_t)(kt * 16 + fr) * 3072 + ks * 32 + fg * 8);

  {                                    // prologue: write Vt[0]; prefetch c1
#pragma unroll
    for (int j = 0; j < 8; j++) {
      unsigned pk = (unsigned)v0[j] | ((unsigned)v1[j] << 16);
      *(unsigned*)(Vt0 + swz(vcc * 8 + j, 4 * vpr)) = pk;
    }
    v0 = *(const u16x8*)(Vp + (size_t)64 * 3072);
    v1 = *(const u16x8*)(Vp + (size_t)65 * 3072);
  }

  for (int c = 0; c < 4; c++) {
    __syncthreads();                   // Vt[c&1] written by all; PV(c-1) done
    if (c < 3) {                       // write Vt[(c+1)&1] from regs
      char* VtN = Vt0 + ((c + 1) & 1) * 8192;
#pragma unroll
      for (int j = 0; j < 8; j++) {
        unsigned pk = (unsigned)v0[j] | ((unsigned)v1[j] << 16);
        *(unsigned*)(VtN + swz(vcc * 8 + j, 4 * vpr)) = pk;
      }
      if (c < 2) {
        v0 = *(const u16x8*)(Vp + (size_t)(c + 2) * 64 * 3072);
        v1 = *(const u16x8*)(Vp + (size_t)((c + 2) * 64 + 1) * 3072);
      }
    }

    f32x4 s[4][4] = {};                // RAW S^T [key-tile][q-tile]
#pragma unroll
    for (int ks = 0; ks < 2; ks++)
#pragma unroll
      for (int kt = 0; kt < 4; kt++)
#pragma unroll
        for (int mq = 0; mq < 4; mq++) mfma16(s[kt][mq], kf[ks][kt], qf[mq][ks]);
    if (c < 3) {                       // prefetch next K (lands under SM+PV)
#pragma unroll
      for (int kt = 0; kt < 4; kt++)
#pragma unroll
        for (int ks = 0; ks < 2; ks++)
          kf[ks][kt] = *(const u16x8*)(Kb + (size_t)((c + 1) * 64 + kt * 16 + fr) * 3072 + ks * 32 + fg * 8);
    }

#pragma unroll
    for (int mq = 0; mq < 4; mq++) {
      float v = -1e30f;
#pragma unroll
      for (int kt = 0; kt < 4; kt++)
#pragma unroll
        for (int reg = 0; reg < 4; reg++) v = fmaxf(v, s[kt][mq][reg]);
      v = fmaxf(v, __shfl_xor(v, 16));
      v = fmaxf(v, __shfl_xor(v, 32));
      v *= C1;
      if (!__all(v <= mrun[mq] + 8.f)) {          // T13 defer-max
        float mn = fmaxf(mrun[mq], v);
        float alpha = exp2r(mrun[mq] - mn);
        mrun[mq] = mn;
        lrun[mq] *= alpha;
#pragma unroll
        for (int dt = 0; dt < 4; dt++) o[dt][mq] *= alpha;
      }
      float mn = mrun[mq];
      int q = mq * 16 + fr;
      float rs = 0.f;
#pragma unroll
      for (int kt = 0; kt < 4; kt++) {
        f32x4 p;
#pragma unroll
        for (int reg = 0; reg < 4; reg++)
          p[reg] = exp2r(fmaf(s[kt][mq][reg], C1, -mn));
        rs += p[0] + p[1] + p[2] + p[3];
        uint2 w;
        w.x = (unsigned)f2h(p[0]) | ((unsigned)f2h(p[1]) << 16);
        w.y = (unsigned)f2h(p[2]) | ((unsigned)f2h(p[3]) << 16);
        *(uint2*)(Pw + swz(q, kt * 32 + fg * 8)) = w;
      }
      rs += __shfl_xor(rs, 16);
      rs += __shfl_xor(rs, 32);
      lrun[mq] += rs;
    }
    char* VtB = Vt0 + (c & 1) * 8192;
#pragma unroll
    for (int ks = 0; ks < 2; ks++) {
      u16x8 vf[4], pf[4];
#pragma unroll
      for (int dt = 0; dt < 4; dt++)
        vf[dt] = *(const u16x8*)(VtB + swz(dt * 16 + fr, ks * 64 + fg * 16));
#pragma unroll
      for (int mq = 0; mq < 4; mq++)
        pf[mq] = *(const u16x8*)(Pw + swz(mq * 16 + fr, ks * 64 + fg * 16));
#pragma unroll
      for (int dt = 0; dt < 4; dt++)
#pragma unroll
        for (int mq = 0; mq < 4; mq++) mfma16(o[dt][mq], vf[dt], pf[mq]);
    }
  }

#pragma unroll
  for (int mq = 0; mq < 4; mq++) {
    float rl = 1.0f / lrun[mq];
    size_t row = rowbase + qr + mq * 16 + fr;
#pragma unroll
    for (int dt = 0; dt < 4; dt++) {
      uint2 w;
      w.x = (unsigned)f2h(o[dt][mq][0] * rl) | ((unsigned)f2h(o[dt][mq][1] * rl) << 16);
      w.y = (unsigned)f2h(o[dt][mq][2] * rl) | ((unsigned)f2h(o[dt][mq][3] * rl) << 16);
      *(uint2*)(aout + row * 1024 + h * 64 + dt * 16 + fg * 4) = w;
    }
  }
}

__device__ __forceinline__ void attn_act_body(
    const unsigned short* __restrict__ qa, const unsigned short* __restrict__ kv,
    unsigned short* __restrict__ aout, int bid, char* smem) {
  int h = bid & 15, b = bid >> 4;
  int tid = threadIdx.x, lane = tid & 63, wid = tid >> 6;
  int fr = lane & 15, fg = lane >> 4;
  const unsigned short* Qb = qa + (size_t)b * 57 * 1024 + h * 64;
  const unsigned short* Kb = kv + (size_t)b * 769 * 2048 + h * 64;
  const unsigned short* Vb = Kb + 1024;

  char* Vw = smem + wid * 8192;                 // [4][64*64]
  char* Pw = smem + 32768 + wid * 8192;         // [4][64*64]
  float* Ml = (float*)(smem + 65536);           // [4][64]
  float* Ll = (float*)(smem + 65536 + 1024);    // [4][64]

  u16x8 qf[4][2];
#pragma unroll
  for (int mq = 0; mq < 4; mq++) {
    int q = mq * 16 + fr;
    if (q > 56) q = 56;
#pragma unroll
    for (int ks = 0; ks < 2; ks++)
      qf[mq][ks] = *(const u16x8*)(Qb + (size_t)q * 1024 + ks * 32 + fg * 8);
  }
  f32x4 o[4][4] = {};
  float mrun[4], lrun[4];
#pragma unroll
  for (int mq = 0; mq < 4; mq++) { mrun[mq] = -1e30f; lrun[mq] = 0.f; }

  u16x8 kf[2][4];
  {                                            // preload K for first chunk
    int kc0 = wid * 64;
#pragma unroll
    for (int kt = 0; kt < 4; kt++) {
      int krow = kc0 + kt * 16 + fr;
      if (krow > 768) krow = 768;
#pragma unroll
      for (int ks = 0; ks < 2; ks++)
        kf[ks][kt] = *(const u16x8*)(Kb + (size_t)krow * 2048 + ks * 32 + fg * 8);
    }
  }

  int vpr = lane & 31;                         // 2-way-bank V staging coords
  for (int c = wid; c < 13; c += 4) {
    int kc0 = c * 64;
#pragma unroll
    for (int i = 0; i < 4; i++) {              // V^T staging (pair-packed b32)
      int cv = i * 2 + (lane >> 5);
      int kr0 = kc0 + 2 * vpr, kr1 = kc0 + 2 * vpr + 1;
      if (kr0 > 768) kr0 = 768;
      if (kr1 > 768) kr1 = 768;
      u16x8 v0 = *(const u16x8*)(Vb + (size_t)kr0 * 2048 + cv * 8);
      u16x8 v1 = *(const u16x8*)(Vb + (size_t)kr1 * 2048 + cv * 8);
#pragma unroll
      for (int j = 0; j < 8; j++) {
        unsigned pk = (unsigned)v0[j] | ((unsigned)v1[j] << 16);
        *(unsigned*)(Vw + swz(cv * 8 + j, 4 * vpr)) = pk;
      }
    }

    f32x4 s[4][4] = {};                        // RAW S^T
#pragma unroll
    for (int ks = 0; ks < 2; ks++)
#pragma unroll
      for (int kt = 0; kt < 4; kt++)
#pragma unroll
        for (int mq = 0; mq < 4; mq++) mfma16(s[kt][mq], kf[ks][kt], qf[mq][ks]);
    if (c + 4 < 13) {                          // prefetch next chunk's K
      int kn = (c + 4) * 64;
#pragma unroll
      for (int kt = 0; kt < 4; kt++) {
        int krow = kn + kt * 16 + fr;
        if (krow > 768) krow = 768;
#pragma unroll
        for (int ks = 0; ks < 2; ks++)
          kf[ks][kt] = *(const u16x8*)(Kb + (size_t)krow * 2048 + ks * 32 + fg * 8);
      }
    }
    if (kc0 + 64 > 769) {                      // mask invalid keys
#pragma unroll
      for (int kt = 0; kt < 4; kt++)
#pragma unroll
        for (int reg = 0; reg < 4; reg++)
          if (kc0 + kt * 16 + fg * 4 + reg >= 769)
#pragma unroll
            for (int mq = 0; mq < 4; mq++) s[kt][mq][reg] = -1e30f;
    }

#pragma unroll
    for (int mq = 0; mq < 4; mq++) {
      float v = -1e30f;
#pragma unroll
      for (int kt = 0; kt < 4; kt++)
#pragma unroll
        for (int reg = 0; reg < 4; reg++) v = fmaxf(v, s[kt][mq][reg]);
      v = fmaxf(v, __shfl_xor(v, 16));
      v = fmaxf(v, __shfl_xor(v, 32));
      v *= C1;
      if (!__all(v <= mrun[mq] + 8.f)) {       // T13 defer-max
        float mn = fmaxf(mrun[mq], v);
        float alpha = exp2r(mrun[mq] - mn);
        mrun[mq] = mn;
        lrun[mq] *= alpha;
#pragma unroll
        for (int dt = 0; dt < 4; dt++) o[dt][mq] *= alpha;
      }
      float mn = mrun[mq];
      int q = mq * 16 + fr;
      float rs = 0.f;
#pragma unroll
      for (int kt = 0; kt < 4; kt++) {
        f32x4 p;
#pragma unroll
        for (int reg = 0; reg < 4; reg++)
          p[reg] = exp2r(fmaf(s[kt][mq][reg], C1, -mn));
        rs += p[0] + p[1] + p[2] + p[3];
        uint2 w;
        w.x = (unsigned)f2h(p[0]) | ((unsigned)f2h(p[1]) << 16);
        w.y = (unsigned)f2h(p[2]) | ((unsigned)f2h(p[3]) << 16);
        *(uint2*)(Pw + swz(q, kt * 32 + fg * 8)) = w;
      }
      rs += __shfl_xor(rs, 16);
      rs += __shfl_xor(rs, 32);
      lrun[mq] += rs;
    }
#pragma unroll
    for (int ks = 0; ks < 2; ks++) {
      u16x8 vf[4], pf[4];
#pragma unroll
      for (int dt = 0; dt < 4; dt++)
        vf[dt] = *(const u16x8*)(Vw + swz(dt * 16 + fr, ks * 64 + fg * 16));
#pragma unroll
      for (int mq = 0; mq < 4; mq++)
        pf[mq] = *(const u16x8*)(Pw + swz(mq * 16 + fr, ks * 64 + fg * 16));
#pragma unroll
      for (int dt = 0; dt < 4; dt++)
#pragma unroll
        for (int mq = 0; mq < 4; mq++) mfma16(o[dt][mq], vf[dt], pf[mq]);
    }
  }

  // ---- combine wave partials (flash merge) ----
  __syncthreads();
  if (fg == 0) {
#pragma unroll
    for (int mq = 0; mq < 4; mq++) {
      Ml[wid * 64 + mq * 16 + fr] = mrun[mq];
      Ll[wid * 64 + mq * 16 + fr] = lrun[mq];
    }
  }
  __syncthreads();
  float* Oac = (float*)smem;                   // 16KB scratch over Vt[0..1]
  for (int i = tid; i < 4096; i += 256) Oac[i] = 0.f;
  __syncthreads();
  for (int w = 0; w < 4; w++) {
    if (wid == w) {
#pragma unroll
      for (int mq = 0; mq < 4; mq++) {
        int q = mq * 16 + fr;
        float Mq = fmaxf(fmaxf(Ml[q], Ml[64 + q]), fmaxf(Ml[128 + q], Ml[192 + q]));
        float f = exp2r(mrun[mq] - Mq);
#pragma unroll
        for (int dt = 0; dt < 4; dt++) {
          int d = dt * 16 + fg * 4;
#pragma unroll
          for (int reg = 0; reg < 4; reg++)
            Oac[(d + reg) * 64 + q] += o[dt][mq][reg] * f;
        }
      }
    }
    __syncthreads();
  }
  for (int i = tid; i < 4096; i += 256) {
    int d = i >> 6, q = i & 63;
    if (q < 57) {
      float Mq = fmaxf(fmaxf(Ml[q], Ml[64 + q]), fmaxf(Ml[128 + q], Ml[192 + q]));
      float Lq = Ll[q] * exp2r(Ml[q] - Mq) + Ll[64 + q] * exp2r(Ml[64 + q] - Mq) +
                 Ll[128 + q] * exp2r(Ml[128 + q] - Mq) + Ll[192 + q] * exp2r(Ml[192 + q] - Mq);
      aout[(size_t)(b * 57 + q) * 1024 + h * 64 + d] = f2h(Oac[i] / Lq);
    }
  }
}

// ---- merged attention: act [0,1024) first, non [1024,4096)
__global__ __launch_bounds__(256, 2) void k_attn(
    const unsigned short* __restrict__ qkv, const unsigned short* __restrict__ qa,
    const unsigned short* __restrict__ kv,
    unsigned short* __restrict__ anon, unsigned short* __restrict__ aact) {
  extern __shared__ char smem[];
  int bid = blockIdx.x;
  if (bid < 1024) attn_act_body(qa, kv, aact, bid, smem);
  else            attn_non_body(qkv, anon, bid - 1024, smem);
}

// ---------------------------------------------------------------------------
extern "C" void kernel_launch(void* const* d_in, const int* in_sizes, int n_in,
                              void* d_out, int out_size, void* d_ws, size_t ws_size,
                              hipStream_t stream) {
  const float* x    = (const float*)d_in[0];
  const float* Wqkv = (const float*)d_in[1];
  const float* Wq   = (const float*)d_in[2];
  const float* Wkv  = (const float*)d_in[3];
  const float* Wpn  = (const float*)d_in[4];
  const float* bpn  = (const float*)d_in[5];
  const float* Wpa  = (const float*)d_in[6];
  const float* bpa  = (const float*)d_in[7];
  float* out = (float*)d_out;
  char* ws = (char*)d_ws;

  unsigned short* xb   = (unsigned short*)(ws + OFF_XB);
  unsigned short* qkv  = (unsigned short*)(ws + OFF_QKV);
  unsigned short* kvb  = (unsigned short*)(ws + OFF_KV);
  unsigned short* qact = (unsigned short*)(ws + OFF_QACT);
  unsigned short* anon = (unsigned short*)(ws + OFF_ANON);
  unsigned short* aact = (unsigned short*)(ws + OFF_AACT);
  unsigned short* WtQKV = (unsigned short*)(ws + OFF_WQKV);
  unsigned short* WtKV  = (unsigned short*)(ws + OFF_WKV);
  unsigned short* WtQ   = (unsigned short*)(ws + OFF_WQ);
  unsigned short* WtPN  = (unsigned short*)(ws + OFF_WPN);
  unsigned short* WtPA  = (unsigned short*)(ws + OFF_WPA);

  hipFuncSetAttribute((const void*)k_gemm_in,
                      hipFuncAttributeMaxDynamicSharedMemorySize, 131072);
  hipFuncSetAttribute((const void*)k_gemm256<1>,
                      hipFuncAttributeMaxDynamicSharedMemorySize, 131072);
  hipFuncSetAttribute((const void*)k_attn,
                      hipFuncAttributeMaxDynamicSharedMemorySize, 67584);

  // prep: cast (blocks [0,2048)) + weight transpose ([2048,10240))
  k_prep<<<10240, 256, 0, stream>>>(x, xb, 6758400, Wqkv, Wkv, Wq, Wpn, Wpa,
                                    WtQKV, WtKV, WtQ, WtPN, WtPA);

  // ALL input GEMMs in one launch (qkv + kv + q_act; tail-wave backfill)
  k_gemm_in<<<3908, 512, 131072, stream>>>(xb, WtQKV, WtKV, WtQ,
                                           qkv, kvb, qact);

  // merged attention (act + non in one grid)
  k_attn<<<4096, 256, 67584, stream>>>(qkv, qact, kvb, anon, aact);

  // output projections (+bias)
  k_gemm256<1><<<192 * 4, 512, 131072, stream>>>(anon, WtPN, bpn, out,
                                                 49152, 4, 0, 0, 1024, 768, 57);
  k_gemm<1><<<29 * 8, 256, 0, stream>>>(aact, WtPA, bpa, out,
                                        3648, 1024, 0, 0, 1024, 57, 0);
}

// Round 15
// 936.336 us; speedup vs baseline: 1.0685x; 1.0092x over previous
//
#include <hip/hip_runtime.h>
#include <stdint.h>

// ---------------------------------------------------------------------------
// SeparatedAttention on MI355X (gfx950), fp16 MFMA pipeline (fp32 accum).
// Round 15: output projections merged into ONE launch (proj_non 768 blocks +
// proj_act as 60 overlap-tiles of the same 256x256 body; act blocks backfill
// proj_non's straggler wave). 128x128 kernel removed. GEMM body (r12/r14
// BK=64 8-phase, 46% MfmaUtil, 0 conflicts), attention, prep all frozen.
// ---------------------------------------------------------------------------

typedef __attribute__((ext_vector_type(8))) unsigned short u16x8;
typedef __attribute__((ext_vector_type(8))) _Float16 f16x8;
typedef __attribute__((ext_vector_type(4))) float f32x4;

__device__ __forceinline__ unsigned short f2h(float f) {   // RNE fp32->fp16
  _Float16 h = (_Float16)f;
  return __builtin_bit_cast(unsigned short, h);
}

__device__ __forceinline__ float exp2r(float x) {          // raw v_exp_f32
  return __builtin_amdgcn_exp2f(x);
}

__device__ __forceinline__ void mfma16(f32x4& d, u16x8 a, u16x8 b) {
  d = __builtin_amdgcn_mfma_f32_16x16x32_f16(
      __builtin_bit_cast(f16x8, a), __builtin_bit_cast(f16x8, b), d, 0, 0, 0);
}

// async global->LDS, 16B per lane; dest = wave-uniform base + lane*16
__device__ __forceinline__ void async16(void* lds_p, const void* g) {
  __builtin_amdgcn_global_load_lds(
      (const __attribute__((address_space(1))) unsigned int*)g,
      (__attribute__((address_space(3))) unsigned int*)lds_p, 16, 0, 0);
}

// XOR swizzle for [row][128B] LDS tiles (attention)
__device__ __forceinline__ int swz(int row, int bcol) {
  return (row << 7) + (bcol ^ ((row & 7) << 4));
}

// bijective XCD swizzle (m204)
__device__ __forceinline__ int xcd_swz(int bid, int nwg) {
  int q8 = nwg >> 3, r8 = nwg & 7;
  int xcd = bid & 7, idx = bid >> 3;
  return (xcd < r8 ? xcd * (q8 + 1) : r8 * (q8 + 1) + (xcd - r8) * q8) + idx;
}

// ---------------- workspace layout (bytes) ----------------
static constexpr size_t OFF_XB   = 0;                    // x fp16      108.1MB
static constexpr size_t OFF_QKV  = 108134400;            // qkv fp16    302.0MB
static constexpr size_t OFF_KV   = 410124288;            // kv fp16     201.6MB
static constexpr size_t OFF_QACT = 611713024;            // q_act fp16    7.5MB
static constexpr size_t OFF_ANON = 619184128;            // attn_non    100.7MB
static constexpr size_t OFF_AACT = 719847424;            // attn_act      7.5MB
static constexpr size_t OFF_WQKV = 727318528;            // W^T fp16 ...
static constexpr size_t OFF_WKV  = 733609984;
static constexpr size_t OFF_WQ   = 737804288;
static constexpr size_t OFF_WPN  = 739901440;
static constexpr size_t OFF_WPA  = 741998592;            // total 744095744

// -------- merged prep: cast x->fp16 [0,2048) + weight transpose [2048,10240)
__global__ __launch_bounds__(256) void k_prep(
    const float* __restrict__ x, unsigned short* __restrict__ xb, int n8,
    const float* __restrict__ Wqkv, const float* __restrict__ Wkv,
    const float* __restrict__ Wq,   const float* __restrict__ Wpn,
    const float* __restrict__ Wpa,
    unsigned short* __restrict__ Tqkv, unsigned short* __restrict__ Tkv,
    unsigned short* __restrict__ Tq,   unsigned short* __restrict__ Tpn,
    unsigned short* __restrict__ Tpa) {
  int bxg = blockIdx.x;
  if (bxg < 2048) {                       // ---- cast (grid-stride, 32B/iter)
    int stride = 2048 * 256;
    for (int i = bxg * 256 + threadIdx.x; i < n8; i += stride) {
      float4 v0 = ((const float4*)x)[i * 2];
      float4 v1 = ((const float4*)x)[i * 2 + 1];
      uint4 w;
      w.x = (unsigned)f2h(v0.x) | ((unsigned)f2h(v0.y) << 16);
      w.y = (unsigned)f2h(v0.z) | ((unsigned)f2h(v0.w) << 16);
      w.z = (unsigned)f2h(v1.x) | ((unsigned)f2h(v1.y) << 16);
      w.w = (unsigned)f2h(v1.z) | ((unsigned)f2h(v1.w) << 16);
      ((uint4*)xb)[i] = w;
    }
    return;
  }
  // ---- weight transpose+cast (5 weights, flattened 256 x 32 grid)
  __shared__ float ts[32][33];
  int bx2 = bxg - 2048;
  int bx = bx2 & 255, ky = bx2 >> 8;
  const float* W; unsigned short* Wt; int Nc, nb;
  if (bx < 96)       { W = Wqkv; Wt = Tqkv; Nc = 3072; nb = bx; }
  else if (bx < 160) { W = Wkv;  Wt = Tkv;  Nc = 2048; nb = bx - 96; }
  else if (bx < 192) { W = Wq;   Wt = Tq;   Nc = 1024; nb = bx - 160; }
  else if (bx < 224) { W = Wpn;  Wt = Tpn;  Nc = 1024; nb = bx - 192; }
  else               { W = Wpa;  Wt = Tpa;  Nc = 1024; nb = bx - 224; }
  int n0 = nb * 32, k0 = ky * 32;
  int tx = threadIdx.x & 31, ty = threadIdx.x >> 5;   // 32 x 8
#pragma unroll
  for (int i = 0; i < 4; i++) {
    int k = ty + i * 8;
    ts[k][tx] = W[(size_t)(k0 + k) * Nc + n0 + tx];
  }
  __syncthreads();
#pragma unroll
  for (int i = 0; i < 4; i++) {
    int n = ty + i * 8;
    Wt[(size_t)(n0 + n) * 1024 + k0 + tx] = f2h(ts[tx][n]);
  }
}

// ========== 256x256 8-phase pipelined GEMM body (r12-exact, BK=64) =========
// K=1024 -> 16 K-tiles, 8 iterations x 8 phases (2 K-tiles/iter).
// Barrier set (6/iter): end of p1,p3,p4(+vmcnt6),p5,p7,p8(+vmcnt6).
template <int EPI>
__device__ __forceinline__ void gemm256_body(
    const unsigned short* __restrict__ A, const unsigned short* __restrict__ Bt,
    const float* __restrict__ bias, void* __restrict__ outp,
    int M, int NTN, int arpb, int aoff, int ldo, int orpb, int ooff,
    int wg, char* lds) {
  int tid = threadIdx.x, lane = tid & 63, wid = tid >> 6;
  int fr = lane & 15, fg = lane >> 4;

  int mt = wg / NTN, nt = wg - mt * NTN;
  int r0 = mt << 8, n0 = nt << 8;
  if (r0 > M - 256) r0 = M - 256;                    // overlap tile

  const unsigned short* pA[2][2];   // [a][j]
  const unsigned short* pB[2][2];   // [b][j]
#pragma unroll
  for (int j = 0; j < 2; j++) {
    int rc = (wid * 2 + j) * 8 + (lane >> 3);        // rho within chunk 0..127
    int cc = (lane & 7) ^ (rc & 7);                  // inverse-swizzled chunk
#pragma unroll
    for (int a = 0; a < 2; a++) {
      int row = (rc >> 6) * 128 + a * 64 + (rc & 63);
      int r = r0 + row;
      if (r >= M) r = M - 1;
      size_t gr;
      if (arpb > 0) { int bb = r / arpb; gr = (size_t)bb * 825 + aoff + (r - bb * arpb); }
      else gr = (size_t)r;
      pA[a][j] = A + gr * 1024 + cc * 8;
    }
#pragma unroll
    for (int b = 0; b < 2; b++) {
      int n = ((rc >> 5) & 3) * 64 + b * 32 + (rc & 31);
      pB[b][j] = Bt + (size_t)(n0 + n) * 1024 + cc * 8;
    }
  }

  int wr = wid >> 2, wc = wid & 3;                   // 2(M) x 4(N) waves
  int ch0 = fg ^ (fr & 7);
  int aoff0 = (wr * 64 + fr) * 128 + ch0 * 16;
  int boff0 = (wc * 32 + fr) * 128 + ch0 * 16;

  u16x8 afr[8], bf0[4], bf1[4];
  f32x4 acc[8][4] = {};

#define BAR  asm volatile("s_barrier" ::: "memory")
#define VM6  asm volatile("s_waitcnt vmcnt(6)" ::: "memory")
#define VM0  asm volatile("s_waitcnt vmcnt(0)" ::: "memory")

  auto LDA = [&](int d, int a) {                     // 8 x ds_read_b128
    char* base = lds + d * 65536 + a * 16384;
#pragma unroll
    for (int mm = 0; mm < 4; mm++)
#pragma unroll
      for (int ks = 0; ks < 2; ks++)
        afr[mm * 2 + ks] = *(const u16x8*)(base + mm * 2048 + (aoff0 ^ (ks * 64)));
  };
  auto LDB = [&](int d, int b, u16x8* bf) {          // 4 x ds_read_b128
    char* base = lds + d * 65536 + 32768 + b * 16384;
#pragma unroll
    for (int nn = 0; nn < 2; nn++)
#pragma unroll
      for (int ks = 0; ks < 2; ks++)
        bf[nn * 2 + ks] = *(const u16x8*)(base + nn * 2048 + (boff0 ^ (ks * 64)));
  };
  auto STAGE_A = [&](int d, int a, int t) {
#pragma unroll
    for (int j = 0; j < 2; j++)
      async16(lds + d * 65536 + a * 16384 + ((wid * 2 + j) << 10), pA[a][j] + t * 64);
  };
  auto STAGE_B = [&](int d, int b, int t) {
#pragma unroll
    for (int j = 0; j < 2; j++)
      async16(lds + d * 65536 + 32768 + b * 16384 + ((wid * 2 + j) << 10), pB[b][j] + t * 64);
  };
  auto CLUSTER = [&](int a, int b, u16x8* bf) {      // 16 MFMA, one C-quadrant
    __builtin_amdgcn_s_setprio(1);
#pragma unroll
    for (int mm = 0; mm < 4; mm++)
#pragma unroll
      for (int nn = 0; nn < 2; nn++)
#pragma unroll
        for (int ks = 0; ks < 2; ks++)
          mfma16(acc[a * 4 + mm][b * 2 + nn], afr[mm * 2 + ks], bf[nn * 2 + ks]);
    __builtin_amdgcn_s_setprio(0);
  };

  STAGE_A(0, 0, 0); STAGE_B(0, 0, 0); STAGE_B(0, 1, 0); STAGE_A(0, 1, 0);
  STAGE_A(1, 0, 1); STAGE_B(1, 0, 1); STAGE_B(1, 1, 1);
  VM6; BAR;

#pragma unroll 1
  for (int i = 0; i < 8; i++) {
    bool nl = (i < 7);
    int t1 = 2 * i + 1, t2 = 2 * i + 2, t3 = 2 * i + 3;
    // p1
    LDA(0, 0); LDB(0, 0, bf0);
    STAGE_A(1, 1, t1);
    CLUSTER(0, 0, bf0); BAR;
    // p2 (no end barrier)
    LDB(0, 1, bf1);
    if (nl) STAGE_A(0, 0, t2);
    CLUSTER(0, 1, bf1);
    // p3
    LDA(0, 1);
    if (nl) STAGE_B(0, 0, t2);
    CLUSTER(1, 0, bf0); BAR;
    // p4
    if (nl) STAGE_B(0, 1, t2);
    CLUSTER(1, 1, bf1);
    if (nl) { VM6; } else { VM0; }
    BAR;
    // p5
    LDA(1, 0); LDB(1, 0, bf0);
    if (nl) STAGE_A(0, 1, t2);
    CLUSTER(0, 0, bf0); BAR;
    // p6 (no end barrier)
    LDB(1, 1, bf1);
    if (nl) STAGE_A(1, 0, t3);
    CLUSTER(0, 1, bf1);
    // p7
    LDA(1, 1);
    if (nl) STAGE_B(1, 0, t3);
    CLUSTER(1, 0, bf0); BAR;
    // p8
    if (nl) STAGE_B(1, 1, t3);
    CLUSTER(1, 1, bf1);
    if (nl) { VM6; } else { VM0; }
    BAR;
  }
#undef BAR
#undef VM6
#undef VM0

  // ---- epilogue ----
  int coln[4];
#pragma unroll
  for (int n = 0; n < 4; n++)
    coln[n] = n0 + wc * 64 + (n >> 1) * 32 + (n & 1) * 16 + fr;
  if (EPI == 0) {
    unsigned short* o = (unsigned short*)outp;
#pragma unroll
    for (int m = 0; m < 8; m++)
#pragma unroll
      for (int reg = 0; reg < 4; reg++) {
        int r = r0 + wr * 128 + (m >> 2) * 64 + (m & 3) * 16 + (lane >> 4) * 4 + reg;
        if (r < M) {
          size_t base = (size_t)r * ldo;
#pragma unroll
          for (int n = 0; n < 4; n++) o[base + coln[n]] = f2h(acc[m][n][reg]);
        }
      }
  } else {
    float* o = (float*)outp;
#pragma unroll
    for (int m = 0; m < 8; m++)
#pragma unroll
      for (int reg = 0; reg < 4; reg++) {
        int r = r0 + wr * 128 + (m >> 2) * 64 + (m & 3) * 16 + (lane >> 4) * 4 + reg;
        if (r < M) {
          int bb = r / orpb;
          size_t orow = (size_t)bb * 825 + ooff + (r - bb * orpb);
          size_t base = orow * 1024;
#pragma unroll
          for (int n = 0; n < 4; n++)
            o[base + coln[n]] = acc[m][n][reg] + bias[coln[n]];
        }
      }
  }
}

// ---- merged input GEMMs: qkv [0,2304) + kv [2304,3848) + q_act [3848,3908)
__global__ __launch_bounds__(512, 2) void k_gemm_in(
    const unsigned short* __restrict__ xb,
    const unsigned short* __restrict__ WtQKV,
    const unsigned short* __restrict__ WtKV,
    const unsigned short* __restrict__ WtQ,
    unsigned short* __restrict__ qkv, unsigned short* __restrict__ kvb,
    unsigned short* __restrict__ qact) {
  extern __shared__ char lds[];
  int bid = blockIdx.x;
  if (bid < 2304) {
    gemm256_body<0>(xb, WtQKV, nullptr, qkv, 49152, 12, 768, 57, 3072, 0, 0,
                    xcd_swz(bid, 2304), lds);
  } else if (bid < 3848) {
    gemm256_body<0>(xb, WtKV, nullptr, kvb, 49216, 8, 769, 56, 2048, 0, 0,
                    xcd_swz(bid - 2304, 1544), lds);
  } else {
    gemm256_body<0>(xb, WtQ, nullptr, qact, 3648, 4, 57, 0, 1024, 0, 0,
                    xcd_swz(bid - 3848, 60), lds);
  }
}

// ---- merged output projections: proj_non [0,768) + proj_act [768,828) ----
__global__ __launch_bounds__(512, 2) void k_gemm_out(
    const unsigned short* __restrict__ anon,
    const unsigned short* __restrict__ aact,
    const unsigned short* __restrict__ WtPN,
    const unsigned short* __restrict__ WtPA,
    const float* __restrict__ bpn, const float* __restrict__ bpa,
    float* __restrict__ out) {
  extern __shared__ char lds[];
  int bid = blockIdx.x;
  if (bid < 768) {
    gemm256_body<1>(anon, WtPN, bpn, out, 49152, 4, 0, 0, 1024, 768, 57,
                    xcd_swz(bid, 768), lds);
  } else {
    gemm256_body<1>(aact, WtPA, bpa, out, 3648, 4, 0, 0, 1024, 57, 0,
                    xcd_swz(bid - 768, 60), lds);
  }
}

// ================= attention bodies (merged kernel, r12 frozen) ============
static constexpr float C1 = 0.125f * 1.44269504089f;      // scale * log2(e)

__device__ __forceinline__ void attn_non_body(
    const unsigned short* __restrict__ qkv, unsigned short* __restrict__ aout,
    int bid, char* smem) {
  int h = bid & 15, t = bid >> 4;
  int g = t % 3, b = t / 3;
  int tid = threadIdx.x, lane = tid & 63, wid = tid >> 6;
  int fr = lane & 15, fg = lane >> 4;
  size_t rowbase = (size_t)(b * 768 + g * 256);
  const unsigned short* Qb = qkv + rowbase * 3072 + h * 64;
  const unsigned short* Kb = Qb + 1024;
  const unsigned short* Vb = Qb + 2048;

  char* Vt0 = smem;                    // [2][64*64] fp16 dbuf
  char* Pw = smem + 16384 + wid * 8192;

  int qr = wid * 64;
  u16x8 qf[4][2];
#pragma unroll
  for (int mq = 0; mq < 4; mq++)
#pragma unroll
    for (int ks = 0; ks < 2; ks++)
      qf[mq][ks] = *(const u16x8*)(Qb + (size_t)(qr + mq * 16 + fr) * 3072 + ks * 32 + fg * 8);

  f32x4 o[4][4] = {};
  float mrun[4], lrun[4];
#pragma unroll
  for (int mq = 0; mq < 4; mq++) { mrun[mq] = -1e30f; lrun[mq] = 0.f; }

  int vpr = lane & 31;                 // 2-way-bank V staging coords
  int vcc = wid * 2 + (lane >> 5);
  const unsigned short* Vp = Vb + (size_t)(2 * vpr) * 3072 + vcc * 8;

  u16x8 v0 = *(const u16x8*)(Vp);
  u16x8 v1 = *(const u16x8*)(Vp + 3072);
  u16x8 kf[2][4];
#pragma unroll
  for (int kt = 0; kt < 4; kt++)
#pragma unroll
    for (int ks = 0; ks < 2; ks++)
      kf[ks][kt] = *(const u16x8*)(Kb + (size_t)(kt * 16 + fr) * 3072 + ks * 32 + fg * 8);

  {                                    // prologue: write Vt[0]; prefetch c1
#pragma unroll
    for (int j = 0; j < 8; j++) {
      unsigned pk = (unsigned)v0[j] | ((unsigned)v1[j] << 16);
      *(unsigned*)(Vt0 + swz(vcc * 8 + j, 4 * vpr)) = pk;
    }
    v0 = *(const u16x8*)(Vp + (size_t)64 * 3072);
    v1 = *(const u16x8*)(Vp + (size_t)65 * 3072);
  }

  for (int c = 0; c < 4; c++) {
    __syncthreads();                   // Vt[c&1] written by all; PV(c-1) done
    if (c < 3) {                       // write Vt[(c+1)&1] from regs
      char* VtN = Vt0 + ((c + 1) & 1) * 8192;
#pragma unroll
      for (int j = 0; j < 8; j++) {
        unsigned pk = (unsigned)v0[j] | ((unsigned)v1[j] << 16);
        *(unsigned*)(VtN + swz(vcc * 8 + j, 4 * vpr)) = pk;
      }
      if (c < 2) {
        v0 = *(const u16x8*)(Vp + (size_t)(c + 2) * 64 * 3072);
        v1 = *(const u16x8*)(Vp + (size_t)((c + 2) * 64 + 1) * 3072);
      }
    }

    f32x4 s[4][4] = {};                // RAW S^T [key-tile][q-tile]
#pragma unroll
    for (int ks = 0; ks < 2; ks++)
#pragma unroll
      for (int kt = 0; kt < 4; kt++)
#pragma unroll
        for (int mq = 0; mq < 4; mq++) mfma16(s[kt][mq], kf[ks][kt], qf[mq][ks]);
    if (c < 3) {                       // prefetch next K (lands under SM+PV)
#pragma unroll
      for (int kt = 0; kt < 4; kt++)
#pragma unroll
        for (int ks = 0; ks < 2; ks++)
          kf[ks][kt] = *(const u16x8*)(Kb + (size_t)((c + 1) * 64 + kt * 16 + fr) * 3072 + ks * 32 + fg * 8);
    }

#pragma unroll
    for (int mq = 0; mq < 4; mq++) {
      float v = -1e30f;
#pragma unroll
      for (int kt = 0; kt < 4; kt++)
#pragma unroll
        for (int reg = 0; reg < 4; reg++) v = fmaxf(v, s[kt][mq][reg]);
      v = fmaxf(v, __shfl_xor(v, 16));
      v = fmaxf(v, __shfl_xor(v, 32));
      v *= C1;
      if (!__all(v <= mrun[mq] + 8.f)) {          // T13 defer-max
        float mn = fmaxf(mrun[mq], v);
        float alpha = exp2r(mrun[mq] - mn);
        mrun[mq] = mn;
        lrun[mq] *= alpha;
#pragma unroll
        for (int dt = 0; dt < 4; dt++) o[dt][mq] *= alpha;
      }
      float mn = mrun[mq];
      int q = mq * 16 + fr;
      float rs = 0.f;
#pragma unroll
      for (int kt = 0; kt < 4; kt++) {
        f32x4 p;
#pragma unroll
        for (int reg = 0; reg < 4; reg++)
          p[reg] = exp2r(fmaf(s[kt][mq][reg], C1, -mn));
        rs += p[0] + p[1] + p[2] + p[3];
        uint2 w;
        w.x = (unsigned)f2h(p[0]) | ((unsigned)f2h(p[1]) << 16);
        w.y = (unsigned)f2h(p[2]) | ((unsigned)f2h(p[3]) << 16);
        *(uint2*)(Pw + swz(q, kt * 32 + fg * 8)) = w;
      }
      rs += __shfl_xor(rs, 16);
      rs += __shfl_xor(rs, 32);
      lrun[mq] += rs;
    }
    char* VtB = Vt0 + (c & 1) * 8192;
#pragma unroll
    for (int ks = 0; ks < 2; ks++) {
      u16x8 vf[4], pf[4];
#pragma unroll
      for (int dt = 0; dt < 4; dt++)
        vf[dt] = *(const u16x8*)(VtB + swz(dt * 16 + fr, ks * 64 + fg * 16));
#pragma unroll
      for (int mq = 0; mq < 4; mq++)
        pf[mq] = *(const u16x8*)(Pw + swz(mq * 16 + fr, ks * 64 + fg * 16));
#pragma unroll
      for (int dt = 0; dt < 4; dt++)
#pragma unroll
        for (int mq = 0; mq < 4; mq++) mfma16(o[dt][mq], vf[dt], pf[mq]);
    }
  }

#pragma unroll
  for (int mq = 0; mq < 4; mq++) {
    float rl = 1.0f / lrun[mq];
    size_t row = rowbase + qr + mq * 16 + fr;
#pragma unroll
    for (int dt = 0; dt < 4; dt++) {
      uint2 w;
      w.x = (unsigned)f2h(o[dt][mq][0] * rl) | ((unsigned)f2h(o[dt][mq][1] * rl) << 16);
      w.y = (unsigned)f2h(o[dt][mq][2] * rl) | ((unsigned)f2h(o[dt][mq][3] * rl) << 16);
      *(uint2*)(aout + row * 1024 + h * 64 + dt * 16 + fg * 4) = w;
    }
  }
}

__device__ __forceinline__ void attn_act_body(
    const unsigned short* __restrict__ qa, const unsigned short* __restrict__ kv,
    unsigned short* __restrict__ aout, int bid, char* smem) {
  int h = bid & 15, b = bid >> 4;
  int tid = threadIdx.x, lane = tid & 63, wid = tid >> 6;
  int fr = lane & 15, fg = lane >> 4;
  const unsigned short* Qb = qa + (size_t)b * 57 * 1024 + h * 64;
  const unsigned short* Kb = kv + (size_t)b * 769 * 2048 + h * 64;
  const unsigned short* Vb = Kb + 1024;

  char* Vw = smem + wid * 8192;                 // [4][64*64]
  char* Pw = smem + 32768 + wid * 8192;         // [4][64*64]
  float* Ml = (float*)(smem + 65536);           // [4][64]
  float* Ll = (float*)(smem + 65536 + 1024);    // [4][64]

  u16x8 qf[4][2];
#pragma unroll
  for (int mq = 0; mq < 4; mq++) {
    int q = mq * 16 + fr;
    if (q > 56) q = 56;
#pragma unroll
    for (int ks = 0; ks < 2; ks++)
      qf[mq][ks] = *(const u16x8*)(Qb + (size_t)q * 1024 + ks * 32 + fg * 8);
  }
  f32x4 o[4][4] = {};
  float mrun[4], lrun[4];
#pragma unroll
  for (int mq = 0; mq < 4; mq++) { mrun[mq] = -1e30f; lrun[mq] = 0.f; }

  u16x8 kf[2][4];
  {                                            // preload K for first chunk
    int kc0 = wid * 64;
#pragma unroll
    for (int kt = 0; kt < 4; kt++) {
      int krow = kc0 + kt * 16 + fr;
      if (krow > 768) krow = 768;
#pragma unroll
      for (int ks = 0; ks < 2; ks++)
        kf[ks][kt] = *(const u16x8*)(Kb + (size_t)krow * 2048 + ks * 32 + fg * 8);
    }
  }

  int vpr = lane & 31;                         // 2-way-bank V staging coords
  for (int c = wid; c < 13; c += 4) {
    int kc0 = c * 64;
#pragma unroll
    for (int i = 0; i < 4; i++) {              // V^T staging (pair-packed b32)
      int cv = i * 2 + (lane >> 5);
      int kr0 = kc0 + 2 * vpr, kr1 = kc0 + 2 * vpr + 1;
      if (kr0 > 768) kr0 = 768;
      if (kr1 > 768) kr1 = 768;
      u16x8 v0 = *(const u16x8*)(Vb + (size_t)kr0 * 2048 + cv * 8);
      u16x8 v1 = *(const u16x8*)(Vb + (size_t)kr1 * 2048 + cv * 8);
#pragma unroll
      for (int j = 0; j < 8; j++) {
        unsigned pk = (unsigned)v0[j] | ((unsigned)v1[j] << 16);
        *(unsigned*)(Vw + swz(cv * 8 + j, 4 * vpr)) = pk;
      }
    }

    f32x4 s[4][4] = {};                        // RAW S^T
#pragma unroll
    for (int ks = 0; ks < 2; ks++)
#pragma unroll
      for (int kt = 0; kt < 4; kt++)
#pragma unroll
        for (int mq = 0; mq < 4; mq++) mfma16(s[kt][mq], kf[ks][kt], qf[mq][ks]);
    if (c + 4 < 13) {                          // prefetch next chunk's K
      int kn = (c + 4) * 64;
#pragma unroll
      for (int kt = 0; kt < 4; kt++) {
        int krow = kn + kt * 16 + fr;
        if (krow > 768) krow = 768;
#pragma unroll
        for (int ks = 0; ks < 2; ks++)
          kf[ks][kt] = *(const u16x8*)(Kb + (size_t)krow * 2048 + ks * 32 + fg * 8);
      }
    }
    if (kc0 + 64 > 769) {                      // mask invalid keys
#pragma unroll
      for (int kt = 0; kt < 4; kt++)
#pragma unroll
        for (int reg = 0; reg < 4; reg++)
          if (kc0 + kt * 16 + fg * 4 + reg >= 769)
#pragma unroll
            for (int mq = 0; mq < 4; mq++) s[kt][mq][reg] = -1e30f;
    }

#pragma unroll
    for (int mq = 0; mq < 4; mq++) {
      float v = -1e30f;
#pragma unroll
      for (int kt = 0; kt < 4; kt++)
#pragma unroll
        for (int reg = 0; reg < 4; reg++) v = fmaxf(v, s[kt][mq][reg]);
      v = fmaxf(v, __shfl_xor(v, 16));
      v = fmaxf(v, __shfl_xor(v, 32));
      v *= C1;
      if (!__all(v <= mrun[mq] + 8.f)) {       // T13 defer-max
        float mn = fmaxf(mrun[mq], v);
        float alpha = exp2r(mrun[mq] - mn);
        mrun[mq] = mn;
        lrun[mq] *= alpha;
#pragma unroll
        for (int dt = 0; dt < 4; dt++) o[dt][mq] *= alpha;
      }
      float mn = mrun[mq];
      int q = mq * 16 + fr;
      float rs = 0.f;
#pragma unroll
      for (int kt = 0; kt < 4; kt++) {
        f32x4 p;
#pragma unroll
        for (int reg = 0; reg < 4; reg++)
          p[reg] = exp2r(fmaf(s[kt][mq][reg], C1, -mn));
        rs += p[0] + p[1] + p[2] + p[3];
        uint2 w;
        w.x = (unsigned)f2h(p[0]) | ((unsigned)f2h(p[1]) << 16);
        w.y = (unsigned)f2h(p[2]) | ((unsigned)f2h(p[3]) << 16);
        *(uint2*)(Pw + swz(q, kt * 32 + fg * 8)) = w;
      }
      rs += __shfl_xor(rs, 16);
      rs += __shfl_xor(rs, 32);
      lrun[mq] += rs;
    }
#pragma unroll
    for (int ks = 0; ks < 2; ks++) {
      u16x8 vf[4], pf[4];
#pragma unroll
      for (int dt = 0; dt < 4; dt++)
        vf[dt] = *(const u16x8*)(Vw + swz(dt * 16 + fr, ks * 64 + fg * 16));
#pragma unroll
      for (int mq = 0; mq < 4; mq++)
        pf[mq] = *(const u16x8*)(Pw + swz(mq * 16 + fr, ks * 64 + fg * 16));
#pragma unroll
      for (int dt = 0; dt < 4; dt++)
#pragma unroll
        for (int mq = 0; mq < 4; mq++) mfma16(o[dt][mq], vf[dt], pf[mq]);
    }
  }

  // ---- combine wave partials (flash merge) ----
  __syncthreads();
  if (fg == 0) {
#pragma unroll
    for (int mq = 0; mq < 4; mq++) {
      Ml[wid * 64 + mq * 16 + fr] = mrun[mq];
      Ll[wid * 64 + mq * 16 + fr] = lrun[mq];
    }
  }
  __syncthreads();
  float* Oac = (float*)smem;                   // 16KB scratch over Vt[0..1]
  for (int i = tid; i < 4096; i += 256) Oac[i] = 0.f;
  __syncthreads();
  for (int w = 0; w < 4; w++) {
    if (wid == w) {
#pragma unroll
      for (int mq = 0; mq < 4; mq++) {
        int q = mq * 16 + fr;
        float Mq = fmaxf(fmaxf(Ml[q], Ml[64 + q]), fmaxf(Ml[128 + q], Ml[192 + q]));
        float f = exp2r(mrun[mq] - Mq);
#pragma unroll
        for (int dt = 0; dt < 4; dt++) {
          int d = dt * 16 + fg * 4;
#pragma unroll
          for (int reg = 0; reg < 4; reg++)
            Oac[(d + reg) * 64 + q] += o[dt][mq][reg] * f;
        }
      }
    }
    __syncthreads();
  }
  for (int i = tid; i < 4096; i += 256) {
    int d = i >> 6, q = i & 63;
    if (q < 57) {
      float Mq = fmaxf(fmaxf(Ml[q], Ml[64 + q]), fmaxf(Ml[128 + q], Ml[192 + q]));
      float Lq = Ll[q] * exp2r(Ml[q] - Mq) + Ll[64 + q] * exp2r(Ml[64 + q] - Mq) +
                 Ll[128 + q] * exp2r(Ml[128 + q] - Mq) + Ll[192 + q] * exp2r(Ml[192 + q] - Mq);
      aout[(size_t)(b * 57 + q) * 1024 + h * 64 + d] = f2h(Oac[i] / Lq);
    }
  }
}

// ---- merged attention: act [0,1024) first, non [1024,4096)
__global__ __launch_bounds__(256, 2) void k_attn(
    const unsigned short* __restrict__ qkv, const unsigned short* __restrict__ qa,
    const unsigned short* __restrict__ kv,
    unsigned short* __restrict__ anon, unsigned short* __restrict__ aact) {
  extern __shared__ char smem[];
  int bid = blockIdx.x;
  if (bid < 1024) attn_act_body(qa, kv, aact, bid, smem);
  else            attn_non_body(qkv, anon, bid - 1024, smem);
}

// ---------------------------------------------------------------------------
extern "C" void kernel_launch(void* const* d_in, const int* in_sizes, int n_in,
                              void* d_out, int out_size, void* d_ws, size_t ws_size,
                              hipStream_t stream) {
  const float* x    = (const float*)d_in[0];
  const float* Wqkv = (const float*)d_in[1];
  const float* Wq   = (const float*)d_in[2];
  const float* Wkv  = (const float*)d_in[3];
  const float* Wpn  = (const float*)d_in[4];
  const float* bpn  = (const float*)d_in[5];
  const float* Wpa  = (const float*)d_in[6];
  const float* bpa  = (const float*)d_in[7];
  float* out = (float*)d_out;
  char* ws = (char*)d_ws;

  unsigned short* xb   = (unsigned short*)(ws + OFF_XB);
  unsigned short* qkv  = (unsigned short*)(ws + OFF_QKV);
  unsigned short* kvb  = (unsigned short*)(ws + OFF_KV);
  unsigned short* qact = (unsigned short*)(ws + OFF_QACT);
  unsigned short* anon = (unsigned short*)(ws + OFF_ANON);
  unsigned short* aact = (unsigned short*)(ws + OFF_AACT);
  unsigned short* WtQKV = (unsigned short*)(ws + OFF_WQKV);
  unsigned short* WtKV  = (unsigned short*)(ws + OFF_WKV);
  unsigned short* WtQ   = (unsigned short*)(ws + OFF_WQ);
  unsigned short* WtPN  = (unsigned short*)(ws + OFF_WPN);
  unsigned short* WtPA  = (unsigned short*)(ws + OFF_WPA);

  hipFuncSetAttribute((const void*)k_gemm_in,
                      hipFuncAttributeMaxDynamicSharedMemorySize, 131072);
  hipFuncSetAttribute((const void*)k_gemm_out,
                      hipFuncAttributeMaxDynamicSharedMemorySize, 131072);
  hipFuncSetAttribute((const void*)k_attn,
                      hipFuncAttributeMaxDynamicSharedMemorySize, 67584);

  // prep: cast (blocks [0,2048)) + weight transpose ([2048,10240))
  k_prep<<<10240, 256, 0, stream>>>(x, xb, 6758400, Wqkv, Wkv, Wq, Wpn, Wpa,
                                    WtQKV, WtKV, WtQ, WtPN, WtPA);

  // ALL input GEMMs in one launch (qkv + kv + q_act; tail-wave backfill)
  k_gemm_in<<<3908, 512, 131072, stream>>>(xb, WtQKV, WtKV, WtQ,
                                           qkv, kvb, qact);

  // merged attention (act + non in one grid)
  k_attn<<<4096, 256, 67584, stream>>>(qkv, qact, kvb, anon, aact);

  // merged output projections (+bias) into d_out
  k_gemm_out<<<828, 512, 131072, stream>>>(anon, aact, WtPN, WtPA,
                                           bpn, bpa, out);
}